// Round 1
// baseline (527.119 us; speedup 1.0000x reference)
//
#include <hip/hip_runtime.h>
#include <cstdint>
#include <cstddef>
#include <cstdio>

// ---------------- constants ----------------
#define B_   2
#define T_   1024
#define C_   1024
#define H_   16
#define HS_  64
#define FFN_ 3072

typedef __bf16   bf16x8 __attribute__((ext_vector_type(8)));
typedef float    f32x4  __attribute__((ext_vector_type(4)));
typedef uint16_t u16x8  __attribute__((ext_vector_type(8)));

__device__ __forceinline__ uint16_t f2bf(float f){
  uint32_t u = __float_as_uint(f);
  u += 0x7FFFu + ((u >> 16) & 1u);          // RNE
  return (uint16_t)(u >> 16);
}
__device__ __forceinline__ float bf2f(uint16_t h){
  return __uint_as_float(((uint32_t)h) << 16);
}
__device__ __forceinline__ bf16x8 ldb8(const uint16_t* p){
  return __builtin_bit_cast(bf16x8, *reinterpret_cast<const u16x8*>(p));
}
__device__ __forceinline__ f32x4 mfma16(bf16x8 a, bf16x8 b, f32x4 c){
  return __builtin_amdgcn_mfma_f32_16x16x32_bf16(a, b, c, 0, 0, 0);
}

// ---------------- transpose f32 [R][C] -> bf16 [C][R] ----------------
__global__ __launch_bounds__(256) void k_transpose(const float* __restrict__ in,
                                                   uint16_t* __restrict__ out,
                                                   int R, int Cc){
  __shared__ float tile[32][33];
  int c0 = blockIdx.x*32, r0 = blockIdx.y*32;
  int tx = threadIdx.x, ty = threadIdx.y;   // (32,8)
  #pragma unroll
  for (int i=0;i<4;i++) tile[ty+i*8][tx] = in[(size_t)(r0+ty+i*8)*Cc + c0+tx];
  __syncthreads();
  #pragma unroll
  for (int i=0;i<4;i++) out[(size_t)(c0+ty+i*8)*R + r0+tx] = f2bf(tile[tx][ty+i*8]);
}

// ---------------- LayerNorm (+optional time-shift-half scatter) ----------------
// SHIFT=1: row (b,t) LN -> first half goes to xs[b,t+1], second half to xs[b,t]; xs[b,0][0:512]=0
template<int SHIFT>
__global__ __launch_bounds__(256) void k_ln(const float* __restrict__ in,
                                            const float* __restrict__ w,
                                            const float* __restrict__ bia,
                                            uint16_t* __restrict__ out){
  int row = blockIdx.x;                 // b*T + t
  int t = row & (T_-1);
  const float* xr = in + (size_t)row*C_;
  float4 v = reinterpret_cast<const float4*>(xr)[threadIdx.x];
  float s  = v.x+v.y+v.z+v.w;
  float s2 = v.x*v.x+v.y*v.y+v.z*v.z+v.w*v.w;
  #pragma unroll
  for (int o=1;o<64;o<<=1){ s += __shfl_xor(s,o); s2 += __shfl_xor(s2,o); }
  __shared__ float red[8];
  int lane = threadIdx.x & 63, wid = threadIdx.x >> 6;
  if (lane == 0){ red[wid] = s; red[4+wid] = s2; }
  __syncthreads();
  s  = red[0]+red[1]+red[2]+red[3];
  s2 = red[4]+red[5]+red[6]+red[7];
  float mean = s * (1.f/1024.f);
  float var  = s2 * (1.f/1024.f) - mean*mean;
  float rs   = rsqrtf(var + 1e-5f);
  float vals[4] = {v.x, v.y, v.z, v.w};
  #pragma unroll
  for (int j=0;j<4;j++){
    int cc = threadIdx.x*4 + j;
    float o_ = (vals[j]-mean)*rs*w[cc] + bia[cc];
    uint16_t ob = f2bf(o_);
    if (SHIFT){
      if (cc < 512){
        if (t < T_-1) out[(size_t)(row+1)*C_ + cc] = ob;
        if (t == 0)   out[(size_t)row*C_ + cc] = 0;
      } else {
        out[(size_t)row*C_ + cc] = ob;
      }
    } else {
      out[(size_t)row*C_ + cc] = ob;
    }
  }
}

// ---------------- generic bf16 MFMA GEMM: C = A[M][K] * Bt[N][K]^T (+bias) ----------------
// 256 thr = 4 waves side-by-side in N. Tile 64x128, BK=32.
enum { EPI_QK=0, EPI_VT=1, EPI_WO=2, EPI_BF16=3, EPI_FFN2=4 };

template<int EPI>
__global__ __launch_bounds__(256) void k_gemm(
    const uint16_t* __restrict__ A, const uint16_t* __restrict__ Bt,
    const float* __restrict__ bias, void* __restrict__ outp,
    int M, int N, int K,
    const float* __restrict__ aux0, const float* __restrict__ aux1)
{
  __shared__ uint16_t As[64*40];   // +8 pad -> 80B row stride, 16B aligned, 2-way banks (free)
  __shared__ uint16_t Bs[128*40];
  const int m0 = blockIdx.y*64, n0 = blockIdx.x*128;
  const int tid = threadIdx.x;
  const int lane = tid & 63, wid = tid >> 6;
  const int l16 = lane & 15, lr = lane >> 4;
  const int kq = lr*8;
  const f32x4 z = {0.f,0.f,0.f,0.f};
  f32x4 acc[4][2];
  #pragma unroll
  for (int m=0;m<4;m++){ acc[m][0]=z; acc[m][1]=z; }
  const int ar = tid >> 2, ac = (tid & 3)*8;     // A: 64 rows x 4 chunks(8 elems)
  const int br = tid >> 1, bc = (tid & 1)*16;    // B: 128 rows x 2 chunks(16 elems)
  for (int k0 = 0; k0 < K; k0 += 32){
    u16x8 av  = *reinterpret_cast<const u16x8*>(A  + (size_t)(m0+ar)*K + k0 + ac);
    u16x8 bv0 = *reinterpret_cast<const u16x8*>(Bt + (size_t)(n0+br)*K + k0 + bc);
    u16x8 bv1 = *reinterpret_cast<const u16x8*>(Bt + (size_t)(n0+br)*K + k0 + bc + 8);
    *reinterpret_cast<u16x8*>(As + ar*40 + ac)     = av;
    *reinterpret_cast<u16x8*>(Bs + br*40 + bc)     = bv0;
    *reinterpret_cast<u16x8*>(Bs + br*40 + bc + 8) = bv1;
    __syncthreads();
    bf16x8 af[4], bfr[2];
    #pragma unroll
    for (int m=0;m<4;m++) af[m]  = ldb8(As + (m*16 + l16)*40 + kq);
    #pragma unroll
    for (int n=0;n<2;n++) bfr[n] = ldb8(Bs + (wid*32 + n*16 + l16)*40 + kq);
    #pragma unroll
    for (int m=0;m<4;m++)
      #pragma unroll
      for (int n=0;n<2;n++) acc[m][n] = mfma16(af[m], bfr[n], acc[m][n]);
    __syncthreads();
  }
  #pragma unroll
  for (int m=0;m<4;m++){
    #pragma unroll
    for (int n=0;n<2;n++){
      int col = n0 + wid*32 + n*16 + l16;
      float bc_ = bias ? bias[col] : 0.f;
      #pragma unroll
      for (int r=0;r<4;r++){
        int row = m0 + m*16 + lr*4 + r;
        float v = acc[m][n][r] + bc_;
        if constexpr (EPI == EPI_QK){
          int bb = row >> 10, t = row & (T_-1), h = col >> 6, d = col & 63;
          ((uint16_t*)outp)[((((size_t)bb*H_ + h)*T_ + t)<<6) + d] = f2bf(v);
        } else if constexpr (EPI == EPI_VT){
          int bb = row >> 10, t = row & (T_-1), h = col >> 6, d = col & 63;
          ((uint16_t*)outp)[(((size_t)bb*H_ + h)*HS_ + d)*T_ + t] = f2bf(v);
        } else if constexpr (EPI == EPI_WO){
          int t = row & (T_-1);
          ((float*)outp)[(size_t)row*N + col] = aux1[(size_t)row*N + col] + v*aux0[t];
        } else if constexpr (EPI == EPI_BF16){
          ((uint16_t*)outp)[(size_t)row*N + col] = f2bf(v);
        } else { // EPI_FFN2
          ((float*)outp)[(size_t)row*N + col] = aux0[(size_t)row*N + col] + v;
        }
      }
    }
  }
}

// ---------------- RoPE on first 32 dims of each head (pairs d, d+16) ----------------
__global__ void k_rope(uint16_t* __restrict__ qb, uint16_t* __restrict__ kb){
  int idx = blockIdx.x*256 + threadIdx.x;      // B*H*T*16
  int d  = idx & 15;
  int t  = (idx >> 4) & (T_-1);
  int bh = idx >> 14;
  size_t base = ((size_t)bh*T_ + t)*HS_;
  float invf = powf(10000.f, -(float)d*(1.f/16.f));
  float ang = (float)t * invf;
  float cs = cosf(ang), sn = sinf(ang);
  float q1 = bf2f(qb[base+d]), q2 = bf2f(qb[base+d+16]);
  qb[base+d]    = f2bf(q1*cs - q2*sn);
  qb[base+d+16] = f2bf(q2*cs + q1*sn);
  float k1 = bf2f(kb[base+d]), k2 = bf2f(kb[base+d+16]);
  kb[base+d]    = f2bf(k1*cs - k2*sn);
  kb[base+d+16] = f2bf(k2*cs + k1*sn);
}

// ---------------- pass A: softmax stats (row max m, denom l) via MFMA QK^T ----------------
__global__ __launch_bounds__(256) void k_stats(const uint16_t* __restrict__ q,
                                               const uint16_t* __restrict__ kmat,
                                               float* __restrict__ sm, float* __restrict__ sl){
  int bh = blockIdx.x, qb = blockIdx.y;
  int lane = threadIdx.x & 63, wid = threadIdx.x >> 6;
  int l16 = lane & 15, lr = lane >> 4;
  int r0 = qb*64 + wid*16;
  const uint16_t* qh = q    + (size_t)bh*T_*HS_;
  const uint16_t* kh = kmat + (size_t)bh*T_*HS_;
  int kq = lr*8;
  bf16x8 a0 = ldb8(qh + (size_t)(r0 + l16)*HS_ + kq);
  bf16x8 a1 = ldb8(qh + (size_t)(r0 + l16)*HS_ + kq + 32);
  float m_[4], l_[4]; int rows[4];
  #pragma unroll
  for (int r=0;r<4;r++){ m_[r] = -1e30f; l_[r] = 0.f; rows[r] = r0 + lr*4 + r; }
  int ktmax = (r0 + 15) >> 4;
  for (int kt = 0; kt <= ktmax; kt++){
    bf16x8 b0 = ldb8(kh + (size_t)(kt*16 + l16)*HS_ + kq);
    bf16x8 b1 = ldb8(kh + (size_t)(kt*16 + l16)*HS_ + kq + 32);
    f32x4 s = {0.f,0.f,0.f,0.f};
    s = mfma16(a0, b0, s);
    s = mfma16(a1, b1, s);
    int kcol = kt*16 + l16;
    #pragma unroll
    for (int r=0;r<4;r++){
      float sv = (kcol <= rows[r]) ? s[r]*0.125f : -1e30f;
      float mx = sv;
      mx = fmaxf(mx, __shfl_xor(mx, 1));
      mx = fmaxf(mx, __shfl_xor(mx, 2));
      mx = fmaxf(mx, __shfl_xor(mx, 4));
      mx = fmaxf(mx, __shfl_xor(mx, 8));
      float mn = fmaxf(m_[r], mx);
      float e = (kcol <= rows[r]) ? expf(sv - mn) : 0.f;
      e += __shfl_xor(e, 1);
      e += __shfl_xor(e, 2);
      e += __shfl_xor(e, 4);
      e += __shfl_xor(e, 8);
      l_[r] = l_[r]*expf(m_[r] - mn) + e;
      m_[r] = mn;
    }
  }
  if (l16 == 0){
    #pragma unroll
    for (int r=0;r<4;r++){
      sm[(size_t)bh*T_ + rows[r]] = m_[r];
      sl[(size_t)bh*T_ + rows[r]] = l_[r];
    }
  }
}

// ---------------- pass B: recompute S, p=exp/l, *decay w, head-mix -> c (bf16) ----------------
// decay: w[h,q,k] = time_w[h, 1023-(q-k)] * alpha[h,k] * beta[h,q]  (k<=q)
__global__ __launch_bounds__(256) void k_mix(const uint16_t* __restrict__ q,
    const uint16_t* __restrict__ kmat,
    const float* __restrict__ sm, const float* __restrict__ sl,
    const float* __restrict__ tw, const float* __restrict__ alpha,
    const float* __restrict__ beta, const float* __restrict__ mixw,
    uint16_t* __restrict__ c)
{
  int kt = blockIdx.x, qt = blockIdx.y, b = blockIdx.z;
  if (kt > qt) return;
  __shared__ uint16_t U[16][32][33];
  __shared__ float MW[256];
  int tid = threadIdx.x, lane = tid & 63, wid = tid >> 6;
  int l16 = lane & 15, lr = lane >> 4;
  MW[tid] = mixw[tid];
  int q0 = qt*32, k0 = kt*32;
  int kq = lr*8;
  const f32x4 z = {0.f,0.f,0.f,0.f};
  #pragma unroll
  for (int ih=0; ih<4; ih++){
    int h = wid*4 + ih;
    int bh = b*H_ + h;
    const uint16_t* qh = q    + (size_t)bh*T_*HS_;
    const uint16_t* kh = kmat + (size_t)bh*T_*HS_;
    f32x4 acc[2][2];
    acc[0][0]=z; acc[0][1]=z; acc[1][0]=z; acc[1][1]=z;
    #pragma unroll
    for (int kk=0; kk<2; kk++){
      bf16x8 a0 = ldb8(qh + (size_t)(q0 +      l16)*HS_ + kq + 32*kk);
      bf16x8 a1 = ldb8(qh + (size_t)(q0 + 16 + l16)*HS_ + kq + 32*kk);
      bf16x8 b0 = ldb8(kh + (size_t)(k0 +      l16)*HS_ + kq + 32*kk);
      bf16x8 b1 = ldb8(kh + (size_t)(k0 + 16 + l16)*HS_ + kq + 32*kk);
      acc[0][0] = mfma16(a0,b0,acc[0][0]);
      acc[0][1] = mfma16(a0,b1,acc[0][1]);
      acc[1][0] = mfma16(a1,b0,acc[1][0]);
      acc[1][1] = mfma16(a1,b1,acc[1][1]);
    }
    #pragma unroll
    for (int m=0;m<2;m++){
      #pragma unroll
      for (int n=0;n<2;n++){
        #pragma unroll
        for (int r=0;r<4;r++){
          int ql = m*16 + lr*4 + r, kl = n*16 + l16;
          int qq = q0 + ql, kkc = k0 + kl;
          float u = 0.f;
          if (kkc <= qq){
            float mm = sm[(size_t)bh*T_ + qq];
            float ll = sl[(size_t)bh*T_ + qq];
            float p = expf(acc[m][n][r]*0.125f - mm) / ll;
            u = p * tw[h*T_ + 1023 - (qq - kkc)] * alpha[h*T_ + kkc] * beta[h*T_ + qq];
          }
          U[h][ql][kl] = f2bf(u);
        }
      }
    }
  }
  __syncthreads();
  uint16_t* cw = c + (size_t)b*H_*T_*T_;
  for (int p = tid; p < 1024; p += 256){
    int ql = p >> 5, kl = p & 31;
    float uv[16];
    #pragma unroll
    for (int i=0;i<16;i++) uv[i] = bf2f(U[i][ql][kl]);
    #pragma unroll
    for (int o=0;o<16;o++){
      float s = 0.f;
      #pragma unroll
      for (int i=0;i<16;i++) s += MW[o*16+i]*uv[i];
      cw[((size_t)o*T_ + q0+ql)*T_ + k0+kl] = f2bf(s);
    }
  }
}

// ---------------- PV: y[b,h,q,:] = c[b,h,q,:] @ v  (causal-masked staging) ----------------
__global__ __launch_bounds__(256) void k_pv(const uint16_t* __restrict__ c,
                                            const uint16_t* __restrict__ vT,
                                            uint16_t* __restrict__ y){
  int bh = blockIdx.x, qb = blockIdx.y;
  int b = bh >> 4, h = bh & 15;
  int q0 = qb*64;
  __shared__ uint16_t Cs[64*40];
  __shared__ uint16_t Vs[64*40];
  int tid = threadIdx.x, lane = tid & 63, wid = tid >> 6;
  int l16 = lane & 15, lr = lane >> 4;
  int srow = tid >> 2, scc = (tid & 3)*8;
  const uint16_t* ch = c  + (size_t)bh*T_*T_;
  const uint16_t* vh = vT + (size_t)bh*HS_*T_;
  const f32x4 z = {0.f,0.f,0.f,0.f};
  f32x4 acc[4] = {z,z,z,z};
  int kmax = q0 + 63;
  for (int ks = 0; ks <= kmax; ks += 32){
    int qrow = q0 + srow;
    u16x8 av = *reinterpret_cast<const u16x8*>(ch + (size_t)qrow*T_ + ks + scc);
    #pragma unroll
    for (int e=0;e<8;e++) if (ks + scc + e > qrow) av[e] = 0;   // causal zero
    *reinterpret_cast<u16x8*>(Cs + srow*40 + scc) = av;
    u16x8 bv = *reinterpret_cast<const u16x8*>(vh + (size_t)srow*T_ + ks + scc);
    *reinterpret_cast<u16x8*>(Vs + srow*40 + scc) = bv;
    __syncthreads();
    int kq = lr*8;
    bf16x8 af = ldb8(Cs + (wid*16 + l16)*40 + kq);
    #pragma unroll
    for (int n=0;n<4;n++){
      bf16x8 bf_ = ldb8(Vs + (n*16 + l16)*40 + kq);
      acc[n] = mfma16(af, bf_, acc[n]);
    }
    __syncthreads();
  }
  #pragma unroll
  for (int n=0;n<4;n++){
    #pragma unroll
    for (int r=0;r<4;r++){
      int t = q0 + wid*16 + lr*4 + r;
      int d = n*16 + l16;
      y[((size_t)(b*T_ + t))*C_ + h*HS_ + d] = f2bf(acc[n][r]);
    }
  }
}

// ---------------- GEGLU elementwise: g = gelu_exact(kk) * vv ----------------
__global__ void k_geglu(const uint16_t* __restrict__ kk, const uint16_t* __restrict__ vv,
                        uint16_t* __restrict__ g){
  size_t i = ((size_t)blockIdx.x*256 + threadIdx.x)*8;
  u16x8 a = *reinterpret_cast<const u16x8*>(kk + i);
  u16x8 b = *reinterpret_cast<const u16x8*>(vv + i);
  u16x8 o;
  #pragma unroll
  for (int e=0;e<8;e++){
    float xv = bf2f(a[e]);
    float gl = 0.5f*xv*(1.f + erff(xv*0.70710678118f));
    o[e] = f2bf(gl * bf2f(b[e]));
  }
  *reinterpret_cast<u16x8*>(g + i) = o;
}

// ---------------- host ----------------
extern "C" void kernel_launch(void* const* d_in, const int* in_sizes, int n_in,
                              void* d_out, int out_size, void* d_ws, size_t ws_size,
                              hipStream_t stream)
{
  const float* x      = (const float*)d_in[0];
  const float* ln1w   = (const float*)d_in[1];
  const float* ln1b   = (const float*)d_in[2];
  const float* ln2w   = (const float*)d_in[3];
  const float* ln2b   = (const float*)d_in[4];
  const float* Wq     = (const float*)d_in[5];
  const float* bq     = (const float*)d_in[6];
  const float* Wk     = (const float*)d_in[7];
  const float* bk     = (const float*)d_in[8];
  const float* Wv     = (const float*)d_in[9];
  const float* bv     = (const float*)d_in[10];
  const float* Wo     = (const float*)d_in[11];
  const float* bo     = (const float*)d_in[12];
  const float* tw     = (const float*)d_in[13];
  const float* talpha = (const float*)d_in[14];
  const float* tbeta  = (const float*)d_in[15];
  const float* tgamma = (const float*)d_in[16];
  const float* mixw   = (const float*)d_in[17];
  const float* Wkg    = (const float*)d_in[18];
  const float* bkg    = (const float*)d_in[19];
  const float* Wvg    = (const float*)d_in[20];
  const float* bvg    = (const float*)d_in[21];
  const float* Wwg    = (const float*)d_in[22];
  const float* bwg    = (const float*)d_in[23];

  char* ws = (char*)d_ws;
  size_t off = 0;
  auto alloc = [&](size_t bytes)->char*{
    char* p = ws + off; off += (bytes + 255) & ~(size_t)255; return p;
  };
  uint16_t* WqT  = (uint16_t*)alloc((size_t)C_*C_*2);
  uint16_t* WkT  = (uint16_t*)alloc((size_t)C_*C_*2);
  uint16_t* WvT  = (uint16_t*)alloc((size_t)C_*C_*2);
  uint16_t* WoT  = (uint16_t*)alloc((size_t)C_*C_*2);
  uint16_t* WkgT = (uint16_t*)alloc((size_t)FFN_*C_*2);
  uint16_t* WvgT = (uint16_t*)alloc((size_t)FFN_*C_*2);
  uint16_t* WwgT = (uint16_t*)alloc((size_t)C_*FFN_*2);
  uint16_t* xs   = (uint16_t*)alloc((size_t)B_*T_*C_*2);
  uint16_t* qbuf = (uint16_t*)alloc((size_t)B_*T_*C_*2);
  uint16_t* kbuf = (uint16_t*)alloc((size_t)B_*T_*C_*2);
  uint16_t* vT   = (uint16_t*)alloc((size_t)B_*T_*C_*2);
  float*    sm   = (float*)alloc((size_t)B_*H_*T_*4);
  float*    sl   = (float*)alloc((size_t)B_*H_*T_*4);
  uint16_t* cbuf = (uint16_t*)alloc((size_t)B_*H_*T_*T_*2);   // 64 MB
  uint16_t* ybuf = (uint16_t*)alloc((size_t)B_*T_*C_*2);
  float*    x1   = (float*)alloc((size_t)B_*T_*C_*4);
  // reuse cbuf region for FFN intermediates (36 MB < 64 MB)
  uint16_t* kkb = cbuf;
  uint16_t* vvb = cbuf + (size_t)B_*T_*FFN_/2*1;  // 2048*3072
  uint16_t* gb  = cbuf + (size_t)2048*3072*2;
  vvb = cbuf + (size_t)2048*3072;

  if (off > ws_size){
    fprintf(stderr, "kernel_launch: ws too small (%zu needed, %zu given)\n", off, ws_size);
    return;
  }

  dim3 blk(256);
  dim3 tblk(32,8);
  k_transpose<<<dim3(32,32), tblk, 0, stream>>>(Wq,  WqT,  C_,  C_);
  k_transpose<<<dim3(32,32), tblk, 0, stream>>>(Wk,  WkT,  C_,  C_);
  k_transpose<<<dim3(32,32), tblk, 0, stream>>>(Wv,  WvT,  C_,  C_);
  k_transpose<<<dim3(32,32), tblk, 0, stream>>>(Wo,  WoT,  C_,  C_);
  k_transpose<<<dim3(96,32), tblk, 0, stream>>>(Wkg, WkgT, C_,  FFN_);
  k_transpose<<<dim3(96,32), tblk, 0, stream>>>(Wvg, WvgT, C_,  FFN_);
  k_transpose<<<dim3(32,96), tblk, 0, stream>>>(Wwg, WwgT, FFN_, C_);

  k_ln<1><<<B_*T_, blk, 0, stream>>>(x, ln1w, ln1b, xs);

  k_gemm<EPI_QK><<<dim3(8,32), blk, 0, stream>>>(xs, WqT, bq, qbuf, 2048, 1024, 1024, nullptr, nullptr);
  k_gemm<EPI_QK><<<dim3(8,32), blk, 0, stream>>>(xs, WkT, bk, kbuf, 2048, 1024, 1024, nullptr, nullptr);
  k_gemm<EPI_VT><<<dim3(8,32), blk, 0, stream>>>(xs, WvT, bv, vT,   2048, 1024, 1024, nullptr, nullptr);

  k_rope<<<2048, blk, 0, stream>>>(qbuf, kbuf);
  k_stats<<<dim3(B_*H_, T_/64), blk, 0, stream>>>(qbuf, kbuf, sm, sl);
  k_mix<<<dim3(32,32,B_), blk, 0, stream>>>(qbuf, kbuf, sm, sl, tw, talpha, tbeta, mixw, cbuf);
  k_pv<<<dim3(B_*H_, T_/64), blk, 0, stream>>>(cbuf, vT, ybuf);

  k_gemm<EPI_WO><<<dim3(8,32), blk, 0, stream>>>(ybuf, WoT, bo, x1, 2048, 1024, 1024, tgamma, x);

  k_ln<0><<<B_*T_, blk, 0, stream>>>(x1, ln2w, ln2b, xs);

  k_gemm<EPI_BF16><<<dim3(24,32), blk, 0, stream>>>(xs, WkgT, bkg, kkb, 2048, 3072, 1024, nullptr, nullptr);
  k_gemm<EPI_BF16><<<dim3(24,32), blk, 0, stream>>>(xs, WvgT, bvg, vvb, 2048, 3072, 1024, nullptr, nullptr);
  k_geglu<<<(2048*3072/8)/256, blk, 0, stream>>>(kkb, vvb, gb);
  k_gemm<EPI_FFN2><<<dim3(8,32), blk, 0, stream>>>(gb, WwgT, bwg, d_out, 2048, 1024, 3072, x1, nullptr);
}

// Round 2
// 444.014 us; speedup vs baseline: 1.1872x; 1.1872x over previous
//
#include <hip/hip_runtime.h>
#include <cstdint>
#include <cstddef>
#include <cstdio>

// ---------------- constants ----------------
#define B_   2
#define T_   1024
#define C_   1024
#define H_   16
#define HS_  64
#define FFN_ 3072

typedef __bf16   bf16x8 __attribute__((ext_vector_type(8)));
typedef float    f32x4  __attribute__((ext_vector_type(4)));
typedef uint16_t u16x8  __attribute__((ext_vector_type(8)));

__device__ __forceinline__ uint16_t f2bf(float f){
  uint32_t u = __float_as_uint(f);
  u += 0x7FFFu + ((u >> 16) & 1u);          // RNE
  return (uint16_t)(u >> 16);
}
__device__ __forceinline__ float bf2f(uint16_t h){
  return __uint_as_float(((uint32_t)h) << 16);
}
__device__ __forceinline__ bf16x8 ldb8(const uint16_t* p){
  return __builtin_bit_cast(bf16x8, *reinterpret_cast<const u16x8*>(p));
}
__device__ __forceinline__ f32x4 mfma16(bf16x8 a, bf16x8 b, f32x4 c){
  return __builtin_amdgcn_mfma_f32_16x16x32_bf16(a, b, c, 0, 0, 0);
}

// ---------------- transpose f32 [R][C] -> bf16 [C][R] ----------------
__global__ __launch_bounds__(256) void k_transpose(const float* __restrict__ in,
                                                   uint16_t* __restrict__ out,
                                                   int R, int Cc){
  __shared__ float tile[32][33];
  int c0 = blockIdx.x*32, r0 = blockIdx.y*32;
  int tx = threadIdx.x, ty = threadIdx.y;   // (32,8)
  #pragma unroll
  for (int i=0;i<4;i++) tile[ty+i*8][tx] = in[(size_t)(r0+ty+i*8)*Cc + c0+tx];
  __syncthreads();
  #pragma unroll
  for (int i=0;i<4;i++) out[(size_t)(c0+ty+i*8)*R + r0+tx] = f2bf(tile[tx][ty+i*8]);
}

// ---------------- LayerNorm (+optional time-shift-half scatter) ----------------
template<int SHIFT>
__global__ __launch_bounds__(256) void k_ln(const float* __restrict__ in,
                                            const float* __restrict__ w,
                                            const float* __restrict__ bia,
                                            uint16_t* __restrict__ out){
  int row = blockIdx.x;                 // b*T + t
  int t = row & (T_-1);
  const float* xr = in + (size_t)row*C_;
  float4 v = reinterpret_cast<const float4*>(xr)[threadIdx.x];
  float s  = v.x+v.y+v.z+v.w;
  float s2 = v.x*v.x+v.y*v.y+v.z*v.z+v.w*v.w;
  #pragma unroll
  for (int o=1;o<64;o<<=1){ s += __shfl_xor(s,o); s2 += __shfl_xor(s2,o); }
  __shared__ float red[8];
  int lane = threadIdx.x & 63, wid = threadIdx.x >> 6;
  if (lane == 0){ red[wid] = s; red[4+wid] = s2; }
  __syncthreads();
  s  = red[0]+red[1]+red[2]+red[3];
  s2 = red[4]+red[5]+red[6]+red[7];
  float mean = s * (1.f/1024.f);
  float var  = s2 * (1.f/1024.f) - mean*mean;
  float rs   = rsqrtf(var + 1e-5f);
  float vals[4] = {v.x, v.y, v.z, v.w};
  #pragma unroll
  for (int j=0;j<4;j++){
    int cc = threadIdx.x*4 + j;
    float o_ = (vals[j]-mean)*rs*w[cc] + bia[cc];
    uint16_t ob = f2bf(o_);
    if (SHIFT){
      if (cc < 512){
        if (t < T_-1) out[(size_t)(row+1)*C_ + cc] = ob;
        if (t == 0)   out[(size_t)row*C_ + cc] = 0;
      } else {
        out[(size_t)row*C_ + cc] = ob;
      }
    } else {
      out[(size_t)row*C_ + cc] = ob;
    }
  }
}

// ---------------- generic bf16 MFMA GEMM: C = A[M][K] * Bt[N][K]^T (+bias) ----------------
enum { EPI_QK=0, EPI_VT=1, EPI_WO=2, EPI_BF16=3, EPI_FFN2=4 };

template<int EPI>
__global__ __launch_bounds__(256) void k_gemm(
    const uint16_t* __restrict__ A, const uint16_t* __restrict__ Bt,
    const float* __restrict__ bias, void* __restrict__ outp,
    int M, int N, int K,
    const float* __restrict__ aux0, const float* __restrict__ aux1)
{
  __shared__ uint16_t As[64*40];
  __shared__ uint16_t Bs[128*40];
  const int m0 = blockIdx.y*64, n0 = blockIdx.x*128;
  const int tid = threadIdx.x;
  const int lane = tid & 63, wid = tid >> 6;
  const int l16 = lane & 15, lr = lane >> 4;
  const int kq = lr*8;
  const f32x4 z = {0.f,0.f,0.f,0.f};
  f32x4 acc[4][2];
  #pragma unroll
  for (int m=0;m<4;m++){ acc[m][0]=z; acc[m][1]=z; }
  const int ar = tid >> 2, ac = (tid & 3)*8;
  const int br = tid >> 1, bc = (tid & 1)*16;
  for (int k0 = 0; k0 < K; k0 += 32){
    u16x8 av  = *reinterpret_cast<const u16x8*>(A  + (size_t)(m0+ar)*K + k0 + ac);
    u16x8 bv0 = *reinterpret_cast<const u16x8*>(Bt + (size_t)(n0+br)*K + k0 + bc);
    u16x8 bv1 = *reinterpret_cast<const u16x8*>(Bt + (size_t)(n0+br)*K + k0 + bc + 8);
    *reinterpret_cast<u16x8*>(As + ar*40 + ac)     = av;
    *reinterpret_cast<u16x8*>(Bs + br*40 + bc)     = bv0;
    *reinterpret_cast<u16x8*>(Bs + br*40 + bc + 8) = bv1;
    __syncthreads();
    bf16x8 af[4], bfr[2];
    #pragma unroll
    for (int m=0;m<4;m++) af[m]  = ldb8(As + (m*16 + l16)*40 + kq);
    #pragma unroll
    for (int n=0;n<2;n++) bfr[n] = ldb8(Bs + (wid*32 + n*16 + l16)*40 + kq);
    #pragma unroll
    for (int m=0;m<4;m++)
      #pragma unroll
      for (int n=0;n<2;n++) acc[m][n] = mfma16(af[m], bfr[n], acc[m][n]);
    __syncthreads();
  }
  #pragma unroll
  for (int m=0;m<4;m++){
    #pragma unroll
    for (int n=0;n<2;n++){
      int col = n0 + wid*32 + n*16 + l16;
      float bc_ = bias ? bias[col] : 0.f;
      #pragma unroll
      for (int r=0;r<4;r++){
        int row = m0 + m*16 + lr*4 + r;
        float v = acc[m][n][r] + bc_;
        if constexpr (EPI == EPI_QK){
          int bb = row >> 10, t = row & (T_-1), h = col >> 6, d = col & 63;
          ((uint16_t*)outp)[((((size_t)bb*H_ + h)*T_ + t)<<6) + d] = f2bf(v);
        } else if constexpr (EPI == EPI_VT){
          int bb = row >> 10, t = row & (T_-1), h = col >> 6, d = col & 63;
          ((uint16_t*)outp)[(((size_t)bb*H_ + h)*HS_ + d)*T_ + t] = f2bf(v);
        } else if constexpr (EPI == EPI_WO){
          int t = row & (T_-1);
          ((float*)outp)[(size_t)row*N + col] = aux1[(size_t)row*N + col] + v*aux0[t];
        } else if constexpr (EPI == EPI_BF16){
          ((uint16_t*)outp)[(size_t)row*N + col] = f2bf(v);
        } else { // EPI_FFN2
          ((float*)outp)[(size_t)row*N + col] = aux0[(size_t)row*N + col] + v;
        }
      }
    }
  }
}

// ---------------- RoPE on first 32 dims of each head (pairs d, d+16) ----------------
__global__ void k_rope(uint16_t* __restrict__ qb, uint16_t* __restrict__ kb){
  int idx = blockIdx.x*256 + threadIdx.x;      // B*H*T*16
  int d  = idx & 15;
  int t  = (idx >> 4) & (T_-1);
  int bh = idx >> 14;
  size_t base = ((size_t)bh*T_ + t)*HS_;
  float invf = powf(10000.f, -(float)d*(1.f/16.f));
  float ang = (float)t * invf;
  float cs = cosf(ang), sn = sinf(ang);
  float q1 = bf2f(qb[base+d]), q2 = bf2f(qb[base+d+16]);
  qb[base+d]    = f2bf(q1*cs - q2*sn);
  qb[base+d+16] = f2bf(q2*cs + q1*sn);
  float k1 = bf2f(kb[base+d]), k2 = bf2f(kb[base+d+16]);
  kb[base+d]    = f2bf(k1*cs - k2*sn);
  kb[base+d+16] = f2bf(k2*cs + k1*sn);
}

// ---------------- pass A: softmax stats (row max m, denom l) via MFMA QK^T ----------------
__global__ __launch_bounds__(256) void k_stats(const uint16_t* __restrict__ q,
                                               const uint16_t* __restrict__ kmat,
                                               float* __restrict__ sm, float* __restrict__ sl){
  int bh = blockIdx.x, qb = blockIdx.y;
  int lane = threadIdx.x & 63, wid = threadIdx.x >> 6;
  int l16 = lane & 15, lr = lane >> 4;
  int r0 = qb*64 + wid*16;
  const uint16_t* qh = q    + (size_t)bh*T_*HS_;
  const uint16_t* kh = kmat + (size_t)bh*T_*HS_;
  int kq = lr*8;
  bf16x8 a0 = ldb8(qh + (size_t)(r0 + l16)*HS_ + kq);
  bf16x8 a1 = ldb8(qh + (size_t)(r0 + l16)*HS_ + kq + 32);
  float m_[4], l_[4]; int rows[4];
  #pragma unroll
  for (int r=0;r<4;r++){ m_[r] = -1e30f; l_[r] = 0.f; rows[r] = r0 + lr*4 + r; }
  int ktmax = (r0 + 15) >> 4;
  for (int kt = 0; kt <= ktmax; kt++){
    bf16x8 b0 = ldb8(kh + (size_t)(kt*16 + l16)*HS_ + kq);
    bf16x8 b1 = ldb8(kh + (size_t)(kt*16 + l16)*HS_ + kq + 32);
    f32x4 s = {0.f,0.f,0.f,0.f};
    s = mfma16(a0, b0, s);
    s = mfma16(a1, b1, s);
    int kcol = kt*16 + l16;
    #pragma unroll
    for (int r=0;r<4;r++){
      float sv = (kcol <= rows[r]) ? s[r]*0.125f : -1e30f;
      float mx = sv;
      mx = fmaxf(mx, __shfl_xor(mx, 1));
      mx = fmaxf(mx, __shfl_xor(mx, 2));
      mx = fmaxf(mx, __shfl_xor(mx, 4));
      mx = fmaxf(mx, __shfl_xor(mx, 8));
      float mn = fmaxf(m_[r], mx);
      float e = (kcol <= rows[r]) ? expf(sv - mn) : 0.f;
      e += __shfl_xor(e, 1);
      e += __shfl_xor(e, 2);
      e += __shfl_xor(e, 4);
      e += __shfl_xor(e, 8);
      l_[r] = l_[r]*expf(m_[r] - mn) + e;
      m_[r] = mn;
    }
  }
  if (l16 == 0){
    #pragma unroll
    for (int r=0;r<4;r++){
      sm[(size_t)bh*T_ + rows[r]] = m_[r];
      sl[(size_t)bh*T_ + rows[r]] = l_[r];
    }
  }
}

// ---------------- fused attention: QK^T -> u=p*w -> head-mix -> PV partials ----------------
// grid (kc=8 chunks of 128 k-cols, qt=32 tiles of 32 q-rows, b=2); 512 thr = 8 waves.
// wave w owns input-heads {2w,2w+1} (QK^T/u) and output-heads {2w,2w+1} (PV).
// py[b][qt][kc][o 16][q 32][d 64] f32 partials, reduced by k_yred.
__global__ __launch_bounds__(512, 2) void k_attn(
    const uint16_t* __restrict__ q, const uint16_t* __restrict__ kmat,
    const uint16_t* __restrict__ vT,
    const float* __restrict__ sm, const float* __restrict__ sl,
    const float* __restrict__ tw, const float* __restrict__ alpha,
    const float* __restrict__ beta, const float* __restrict__ mixw,
    float* __restrict__ py)
{
  int kc = blockIdx.x, qt = blockIdx.y, b = blockIdx.z;
  if (4*kc > qt) return;
  const int q0 = qt*32, ck0 = kc*128;
  const int nt = min(4, qt - 4*kc + 1);

  // U[q 32][k pad33][h pad24] u16: q-stride 396 dw (=12 mod 32), k-stride 12 dw -> 2-way reads
  __shared__ uint16_t U[32*33*24 + 32];
  __shared__ float AL[16*128];     // alpha[h][ck0+..]
  __shared__ float TWL[16*160];    // tw[h][992-q0+ck0+..]

  const int tid = threadIdx.x;
  const int lane = tid & 63;
  const int wid = __builtin_amdgcn_readfirstlane(tid >> 6);
  const int l16 = lane & 15, lr = lane >> 4;

  const int base = 992 - q0 + ck0;
  for (int i = tid; i < 16*128; i += 512){
    int h = i >> 7, kk = i & 127;
    AL[i] = alpha[h*1024 + ck0 + kk];
  }
  for (int i = tid; i < 16*160; i += 512){
    int h = i / 160, t = i - h*160;
    int gi = base + t;
    TWL[i] = (gi <= 1023) ? tw[h*1024 + gi] : 0.f;
  }

  // per-lane stats + Q fragments (register-resident across the k loop)
  float SM[2][2][4], BSL[2][2][4];
  bf16x8 qa[2][2][2];
  #pragma unroll
  for (int h2=0; h2<2; ++h2){
    int h = 2*wid + h2, bh = b*16 + h;
    #pragma unroll
    for (int m=0;m<2;m++){
      #pragma unroll
      for (int r=0;r<4;r++){
        int qq = q0 + m*16 + lr*4 + r;
        SM[h2][m][r]  = sm[(size_t)bh*1024 + qq];
        BSL[h2][m][r] = beta[(size_t)h*1024 + qq] / sl[(size_t)bh*1024 + qq];
      }
      #pragma unroll
      for (int kk=0;kk<2;kk++)
        qa[h2][m][kk] = ldb8(q + ((size_t)bh*1024 + q0 + m*16 + l16)*64 + kk*32 + lr*8);
    }
  }
  // mix rows for this wave's 2 output heads (uniform -> SGPR)
  float mw[2][16];
  #pragma unroll
  for (int oo=0;oo<2;oo++)
    #pragma unroll
    for (int i=0;i<16;i++) mw[oo][i] = mixw[(2*wid+oo)*16 + i];

  const f32x4 z = {0.f,0.f,0.f,0.f};
  f32x4 acc[2][2][4];
  #pragma unroll
  for (int oo=0;oo<2;oo++) for (int m=0;m<2;m++) for (int n=0;n<4;n++) acc[oo][m][n] = z;

  __syncthreads();   // AL/TWL ready

  for (int t = 4*kc; t < 4*kc + nt; ++t){
    const int k0 = t*32;
    // ---- QK^T for this wave's 2 heads ----
    f32x4 s[2][2][2];
    #pragma unroll
    for (int h2=0;h2<2;h2++) for (int m=0;m<2;m++) for (int n=0;n<2;n++) s[h2][m][n] = z;
    #pragma unroll
    for (int h2=0;h2<2;h2++){
      const uint16_t* kh = kmat + ((size_t)(b*16 + 2*wid + h2)*1024 + k0)*64;
      #pragma unroll
      for (int kk=0;kk<2;kk++){
        bf16x8 kb0 = ldb8(kh + (size_t)(l16)*64      + kk*32 + lr*8);
        bf16x8 kb1 = ldb8(kh + (size_t)(16 + l16)*64 + kk*32 + lr*8);
        #pragma unroll
        for (int m=0;m<2;m++){
          s[h2][m][0] = mfma16(qa[h2][m][kk], kb0, s[h2][m][0]);
          s[h2][m][1] = mfma16(qa[h2][m][kk], kb1, s[h2][m][1]);
        }
      }
    }
    // ---- u = exp(s/8 - m) * beta/l * alpha * tw  -> U LDS ----
    #pragma unroll
    for (int h2=0;h2<2;h2++){
      int h = 2*wid + h2;
      #pragma unroll
      for (int m=0;m<2;m++){
        #pragma unroll
        for (int n=0;n<2;n++){
          #pragma unroll
          for (int r=0;r<4;r++){
            int qloc = m*16 + lr*4 + r;
            int kloc = n*16 + l16;
            int kg = k0 + kloc;
            float u = 0.f;
            if (kg <= q0 + qloc){
              float p = __expf(s[h2][m][n][r]*0.125f - SM[h2][m][r]) * BSL[h2][m][r];
              u = p * AL[h*128 + (kg - ck0)] * TWL[h*160 + 31 - qloc + (kg - ck0)];
            }
            U[((size_t)qloc*33 + kloc)*24 + h] = f2bf(u);
          }
        }
      }
    }
    __syncthreads();
    // ---- head-mix: c[o][q][k] = sum_i mw[o][i]*u[i]; build PV A-frags in-register ----
    bf16x8 cf[2][2];
    #pragma unroll
    for (int m=0;m<2;m++){
      float ca0[8], ca1[8];
      #pragma unroll
      for (int j=0;j<8;j++){
        int qloc = m*16 + l16;
        int kloc = lr*8 + j;
        const uint16_t* up = U + ((size_t)qloc*33 + kloc)*24;
        u16x8 u0 = *reinterpret_cast<const u16x8*>(up);
        u16x8 u1 = *reinterpret_cast<const u16x8*>(up + 8);
        float c0 = 0.f, c1 = 0.f;
        #pragma unroll
        for (int i=0;i<8;i++){
          float uf = bf2f(u0[i]);
          c0 += mw[0][i]*uf; c1 += mw[1][i]*uf;
        }
        #pragma unroll
        for (int i=0;i<8;i++){
          float uf = bf2f(u1[i]);
          c0 += mw[0][8+i]*uf; c1 += mw[1][8+i]*uf;
        }
        ca0[j] = c0; ca1[j] = c1;
      }
      u16x8 p0, p1;
      #pragma unroll
      for (int j=0;j<8;j++){ p0[j] = f2bf(ca0[j]); p1[j] = f2bf(ca1[j]); }
      cf[0][m] = __builtin_bit_cast(bf16x8, p0);
      cf[1][m] = __builtin_bit_cast(bf16x8, p1);
    }
    // ---- PV for this wave's 2 output heads ----
    #pragma unroll
    for (int oo=0;oo<2;oo++){
      const uint16_t* vh = vT + (size_t)(b*16 + 2*wid + oo)*64*1024;
      #pragma unroll
      for (int n=0;n<4;n++){
        bf16x8 vf = ldb8(vh + (size_t)(n*16 + l16)*1024 + k0 + lr*8);
        #pragma unroll
        for (int m=0;m<2;m++)
          acc[oo][m][n] = mfma16(cf[oo][m], vf, acc[oo][m][n]);
      }
    }
    __syncthreads();   // U consumed; safe to overwrite next tile
  }

  float* po = py + (((size_t)b*32 + qt)*8 + kc)*32768;
  #pragma unroll
  for (int oo=0;oo<2;oo++){
    int o = 2*wid + oo;
    #pragma unroll
    for (int m=0;m<2;m++)
      #pragma unroll
      for (int n=0;n<4;n++)
        #pragma unroll
        for (int r=0;r<4;r++){
          int qloc = m*16 + lr*4 + r;
          po[((size_t)o*32 + qloc)*64 + n*16 + l16] = acc[oo][m][n][r];
        }
  }
}

// ---------------- reduce partials -> ybuf bf16 [B,T,C] ----------------
__global__ void k_yred(const float* __restrict__ py, uint16_t* __restrict__ y){
  int flat = blockIdx.x*256 + threadIdx.x;   // 0..524287, one float4 each
  int d4 = flat & 15, o = (flat>>4)&15, ql = (flat>>8)&31, qt = (flat>>13)&31, b = flat>>18;
  int nch = (qt>>2) + 1;
  const float* p0 = py + (((size_t)b*32 + qt)*8)*32768 + ((size_t)o*32 + ql)*64 + d4*4;
  float4 s = {0.f,0.f,0.f,0.f};
  for (int kc=0; kc<nch; kc++){
    float4 v = *reinterpret_cast<const float4*>(p0 + (size_t)kc*32768);
    s.x += v.x; s.y += v.y; s.z += v.z; s.w += v.w;
  }
  int t = qt*32 + ql;
  uint16_t* yp = y + ((size_t)(b*1024 + t))*1024 + o*64 + d4*4;
  yp[0] = f2bf(s.x); yp[1] = f2bf(s.y); yp[2] = f2bf(s.z); yp[3] = f2bf(s.w);
}

// ---------------- GEGLU elementwise: g = gelu_exact(kk) * vv ----------------
__global__ void k_geglu(const uint16_t* __restrict__ kk, const uint16_t* __restrict__ vv,
                        uint16_t* __restrict__ g){
  size_t i = ((size_t)blockIdx.x*256 + threadIdx.x)*8;
  u16x8 a = *reinterpret_cast<const u16x8*>(kk + i);
  u16x8 b = *reinterpret_cast<const u16x8*>(vv + i);
  u16x8 o;
  #pragma unroll
  for (int e=0;e<8;e++){
    float xv = bf2f(a[e]);
    float gl = 0.5f*xv*(1.f + erff(xv*0.70710678118f));
    o[e] = f2bf(gl * bf2f(b[e]));
  }
  *reinterpret_cast<u16x8*>(g + i) = o;
}

// ---------------- host ----------------
extern "C" void kernel_launch(void* const* d_in, const int* in_sizes, int n_in,
                              void* d_out, int out_size, void* d_ws, size_t ws_size,
                              hipStream_t stream)
{
  const float* x      = (const float*)d_in[0];
  const float* ln1w   = (const float*)d_in[1];
  const float* ln1b   = (const float*)d_in[2];
  const float* ln2w   = (const float*)d_in[3];
  const float* ln2b   = (const float*)d_in[4];
  const float* Wq     = (const float*)d_in[5];
  const float* bq     = (const float*)d_in[6];
  const float* Wk     = (const float*)d_in[7];
  const float* bk     = (const float*)d_in[8];
  const float* Wv     = (const float*)d_in[9];
  const float* bv     = (const float*)d_in[10];
  const float* Wo     = (const float*)d_in[11];
  const float* bo     = (const float*)d_in[12];
  const float* tw     = (const float*)d_in[13];
  const float* talpha = (const float*)d_in[14];
  const float* tbeta  = (const float*)d_in[15];
  const float* tgamma = (const float*)d_in[16];
  const float* mixw   = (const float*)d_in[17];
  const float* Wkg    = (const float*)d_in[18];
  const float* bkg    = (const float*)d_in[19];
  const float* Wvg    = (const float*)d_in[20];
  const float* bvg    = (const float*)d_in[21];
  const float* Wwg    = (const float*)d_in[22];
  const float* bwg    = (const float*)d_in[23];

  char* ws = (char*)d_ws;
  size_t off = 0;
  auto alloc = [&](size_t bytes)->char*{
    char* p = ws + off; off += (bytes + 255) & ~(size_t)255; return p;
  };
  uint16_t* WqT  = (uint16_t*)alloc((size_t)C_*C_*2);
  uint16_t* WkT  = (uint16_t*)alloc((size_t)C_*C_*2);
  uint16_t* WvT  = (uint16_t*)alloc((size_t)C_*C_*2);
  uint16_t* WoT  = (uint16_t*)alloc((size_t)C_*C_*2);
  uint16_t* WkgT = (uint16_t*)alloc((size_t)FFN_*C_*2);
  uint16_t* WvgT = (uint16_t*)alloc((size_t)FFN_*C_*2);
  uint16_t* WwgT = (uint16_t*)alloc((size_t)C_*FFN_*2);
  uint16_t* xs   = (uint16_t*)alloc((size_t)B_*T_*C_*2);
  uint16_t* qbuf = (uint16_t*)alloc((size_t)B_*T_*C_*2);
  uint16_t* kbuf = (uint16_t*)alloc((size_t)B_*T_*C_*2);
  uint16_t* vT   = (uint16_t*)alloc((size_t)B_*T_*C_*2);
  float*    sm   = (float*)alloc((size_t)B_*H_*T_*4);
  float*    sl   = (float*)alloc((size_t)B_*H_*T_*4);
  uint16_t* ybuf = (uint16_t*)alloc((size_t)B_*T_*C_*2);
  float*    x1   = (float*)alloc((size_t)B_*T_*C_*4);
  // 64 MB region: attention partials, then reused for FFN intermediates
  char*     region = alloc((size_t)2*32*8*32768*4);      // 512 * 32768 f32 = 64 MB
  float*    py  = (float*)region;
  uint16_t* kkb = (uint16_t*)region;
  uint16_t* vvb = kkb + (size_t)2048*3072;
  uint16_t* gb  = kkb + (size_t)2*2048*3072;

  if (off > ws_size){
    fprintf(stderr, "kernel_launch: ws too small (%zu needed, %zu given)\n", off, ws_size);
    return;
  }

  dim3 blk(256);
  dim3 tblk(32,8);
  k_transpose<<<dim3(32,32), tblk, 0, stream>>>(Wq,  WqT,  C_,  C_);
  k_transpose<<<dim3(32,32), tblk, 0, stream>>>(Wk,  WkT,  C_,  C_);
  k_transpose<<<dim3(32,32), tblk, 0, stream>>>(Wv,  WvT,  C_,  C_);
  k_transpose<<<dim3(32,32), tblk, 0, stream>>>(Wo,  WoT,  C_,  C_);
  k_transpose<<<dim3(96,32), tblk, 0, stream>>>(Wkg, WkgT, C_,  FFN_);
  k_transpose<<<dim3(96,32), tblk, 0, stream>>>(Wvg, WvgT, C_,  FFN_);
  k_transpose<<<dim3(32,96), tblk, 0, stream>>>(Wwg, WwgT, FFN_, C_);

  k_ln<1><<<B_*T_, blk, 0, stream>>>(x, ln1w, ln1b, xs);

  k_gemm<EPI_QK><<<dim3(8,32), blk, 0, stream>>>(xs, WqT, bq, qbuf, 2048, 1024, 1024, nullptr, nullptr);
  k_gemm<EPI_QK><<<dim3(8,32), blk, 0, stream>>>(xs, WkT, bk, kbuf, 2048, 1024, 1024, nullptr, nullptr);
  k_gemm<EPI_VT><<<dim3(8,32), blk, 0, stream>>>(xs, WvT, bv, vT,   2048, 1024, 1024, nullptr, nullptr);

  k_rope<<<2048, blk, 0, stream>>>(qbuf, kbuf);
  k_stats<<<dim3(B_*H_, T_/64), blk, 0, stream>>>(qbuf, kbuf, sm, sl);
  k_attn<<<dim3(8,32,B_), dim3(512), 0, stream>>>(qbuf, kbuf, vT, sm, sl,
                                                  tw, talpha, tbeta, mixw, py);
  k_yred<<<2048, blk, 0, stream>>>(py, ybuf);

  k_gemm<EPI_WO><<<dim3(8,32), blk, 0, stream>>>(ybuf, WoT, bo, x1, 2048, 1024, 1024, tgamma, x);

  k_ln<0><<<B_*T_, blk, 0, stream>>>(x1, ln2w, ln2b, xs);

  k_gemm<EPI_BF16><<<dim3(24,32), blk, 0, stream>>>(xs, WkgT, bkg, kkb, 2048, 3072, 1024, nullptr, nullptr);
  k_gemm<EPI_BF16><<<dim3(24,32), blk, 0, stream>>>(xs, WvgT, bvg, vvb, 2048, 3072, 1024, nullptr, nullptr);
  k_geglu<<<(2048*3072/8)/256, blk, 0, stream>>>(kkb, vvb, gb);
  k_gemm<EPI_FFN2><<<dim3(8,32), blk, 0, stream>>>(gb, WwgT, bwg, d_out, 2048, 1024, 3072, x1, nullptr);
}

// Round 3
// 403.560 us; speedup vs baseline: 1.3062x; 1.1002x over previous
//
#include <hip/hip_runtime.h>
#include <cstdint>
#include <cstddef>
#include <cstdio>

// ---------------- constants ----------------
#define B_   2
#define T_   1024
#define C_   1024
#define H_   16
#define HS_  64
#define FFN_ 3072

typedef __bf16   bf16x8 __attribute__((ext_vector_type(8)));
typedef float    f32x4  __attribute__((ext_vector_type(4)));
typedef float    f32x16 __attribute__((ext_vector_type(16)));
typedef uint16_t u16x8  __attribute__((ext_vector_type(8)));

__device__ __forceinline__ uint16_t f2bf(float f){
  uint32_t u = __float_as_uint(f);
  u += 0x7FFFu + ((u >> 16) & 1u);          // RNE
  return (uint16_t)(u >> 16);
}
__device__ __forceinline__ float bf2f(uint16_t h){
  return __uint_as_float(((uint32_t)h) << 16);
}
__device__ __forceinline__ bf16x8 ldb8(const uint16_t* p){
  return __builtin_bit_cast(bf16x8, *reinterpret_cast<const u16x8*>(p));
}
__device__ __forceinline__ f32x4 mfma16(bf16x8 a, bf16x8 b, f32x4 c){
  return __builtin_amdgcn_mfma_f32_16x16x32_bf16(a, b, c, 0, 0, 0);
}

// async global->LDS, 16B per lane
typedef __attribute__((address_space(1))) const uint32_t* gas_t;
typedef __attribute__((address_space(3))) uint32_t* las_t;
__device__ __forceinline__ void gl_lds16(const uint16_t* g, uint16_t* l){
  __builtin_amdgcn_global_load_lds((gas_t)g, (las_t)l, 16, 0, 0);
}

// ---------------- transpose f32 [R][C] -> bf16 [C][R] ----------------
__global__ __launch_bounds__(256) void k_transpose(const float* __restrict__ in,
                                                   uint16_t* __restrict__ out,
                                                   int R, int Cc){
  __shared__ float tile[32][33];
  int c0 = blockIdx.x*32, r0 = blockIdx.y*32;
  int tx = threadIdx.x, ty = threadIdx.y;   // (32,8)
  #pragma unroll
  for (int i=0;i<4;i++) tile[ty+i*8][tx] = in[(size_t)(r0+ty+i*8)*Cc + c0+tx];
  __syncthreads();
  #pragma unroll
  for (int i=0;i<4;i++) out[(size_t)(c0+ty+i*8)*R + r0+tx] = f2bf(tile[tx][ty+i*8]);
}

// ---------------- LayerNorm (+optional time-shift-half scatter) ----------------
template<int SHIFT>
__global__ __launch_bounds__(256) void k_ln(const float* __restrict__ in,
                                            const float* __restrict__ w,
                                            const float* __restrict__ bia,
                                            uint16_t* __restrict__ out){
  int row = blockIdx.x;                 // b*T + t
  int t = row & (T_-1);
  const float* xr = in + (size_t)row*C_;
  float4 v = reinterpret_cast<const float4*>(xr)[threadIdx.x];
  float s  = v.x+v.y+v.z+v.w;
  float s2 = v.x*v.x+v.y*v.y+v.z*v.z+v.w*v.w;
  #pragma unroll
  for (int o=1;o<64;o<<=1){ s += __shfl_xor(s,o); s2 += __shfl_xor(s2,o); }
  __shared__ float red[8];
  int lane = threadIdx.x & 63, wid = threadIdx.x >> 6;
  if (lane == 0){ red[wid] = s; red[4+wid] = s2; }
  __syncthreads();
  s  = red[0]+red[1]+red[2]+red[3];
  s2 = red[4]+red[5]+red[6]+red[7];
  float mean = s * (1.f/1024.f);
  float var  = s2 * (1.f/1024.f) - mean*mean;
  float rs   = rsqrtf(var + 1e-5f);
  float vals[4] = {v.x, v.y, v.z, v.w};
  #pragma unroll
  for (int j=0;j<4;j++){
    int cc = threadIdx.x*4 + j;
    float o_ = (vals[j]-mean)*rs*w[cc] + bia[cc];
    uint16_t ob = f2bf(o_);
    if (SHIFT){
      if (cc < 512){
        if (t < T_-1) out[(size_t)(row+1)*C_ + cc] = ob;
        if (t == 0)   out[(size_t)row*C_ + cc] = 0;
      } else {
        out[(size_t)row*C_ + cc] = ob;
      }
    } else {
      out[(size_t)row*C_ + cc] = ob;
    }
  }
}

// ---------------- MFMA GEMM v2: C = A[M][K] * Bt[N][K]^T (+bias) ----------------
// tile 128 x BN, BK=32, 4 waves (2x2), global_load_lds staging (m97 structure)
enum { EPI_QK=0, EPI_VT=1, EPI_WO=2, EPI_BF16=3, EPI_FFN2=4 };

template<int EPI, int BN>
__global__ __launch_bounds__(256) void k_gemm2(
    const uint16_t* __restrict__ A, const uint16_t* __restrict__ Bt,
    const float* __restrict__ bias, void* __restrict__ outp,
    int M, int N, int K,
    const float* __restrict__ aux0, const float* __restrict__ aux1)
{
  __shared__ uint16_t As[128*32];
  __shared__ uint16_t Bs[BN*32];
  const int m0 = blockIdx.y*128, n0 = blockIdx.x*BN;
  const int tid = threadIdx.x;
  const int lane = tid & 63, wid = tid >> 6;
  const int wy = wid >> 1, wx = wid & 1;
  const int l16 = lane & 15, lr = lane >> 4;
  const int WN = BN/2;            // wave cols
  const int NW = BN/32;           // b-frags per wave
  const f32x4 z = {0.f,0.f,0.f,0.f};
  f32x4 acc[4][NW];
  #pragma unroll
  for (int m=0;m<4;m++)
    #pragma unroll
    for (int n=0;n<NW;n++) acc[m][n] = z;
  const int srow = tid >> 2, scol = (tid & 3)*8;
  for (int k0 = 0; k0 < K; k0 += 32){
    gl_lds16(A + (size_t)(m0 + srow)*K      + k0 + scol, As + tid*8);
    gl_lds16(A + (size_t)(m0 + 64 + srow)*K + k0 + scol, As + 2048 + tid*8);
    gl_lds16(Bt + (size_t)(n0 + srow)*K     + k0 + scol, Bs + tid*8);
    if constexpr (BN == 128)
      gl_lds16(Bt + (size_t)(n0 + 64 + srow)*K + k0 + scol, Bs + 2048 + tid*8);
    __syncthreads();
    bf16x8 af[4], bfr[NW];
    #pragma unroll
    for (int m=0;m<4;m++) af[m] = ldb8(As + (wy*64 + m*16 + l16)*32 + lr*8);
    #pragma unroll
    for (int n=0;n<NW;n++) bfr[n] = ldb8(Bs + (wx*WN + n*16 + l16)*32 + lr*8);
    #pragma unroll
    for (int m=0;m<4;m++)
      #pragma unroll
      for (int n=0;n<NW;n++) acc[m][n] = mfma16(af[m], bfr[n], acc[m][n]);
    __syncthreads();
  }
  #pragma unroll
  for (int m=0;m<4;m++){
    #pragma unroll
    for (int n=0;n<NW;n++){
      int col = n0 + wx*WN + n*16 + l16;
      float bc_ = bias ? bias[col] : 0.f;
      #pragma unroll
      for (int r=0;r<4;r++){
        int row = m0 + wy*64 + m*16 + lr*4 + r;
        float v = acc[m][n][r] + bc_;
        if constexpr (EPI == EPI_QK){
          int bb = row >> 10, t = row & (T_-1), h = col >> 6, d = col & 63;
          ((uint16_t*)outp)[((((size_t)bb*H_ + h)*T_ + t)<<6) + d] = f2bf(v);
        } else if constexpr (EPI == EPI_VT){
          int bb = row >> 10, t = row & (T_-1), h = col >> 6, d = col & 63;
          ((uint16_t*)outp)[(((size_t)bb*H_ + h)*HS_ + d)*T_ + t] = f2bf(v);
        } else if constexpr (EPI == EPI_WO){
          int t = row & (T_-1);
          ((float*)outp)[(size_t)row*N + col] = aux1[(size_t)row*N + col] + v*aux0[t];
        } else if constexpr (EPI == EPI_BF16){
          ((uint16_t*)outp)[(size_t)row*N + col] = f2bf(v);
        } else { // EPI_FFN2
          ((float*)outp)[(size_t)row*N + col] = aux0[(size_t)row*N + col] + v;
        }
      }
    }
  }
}

// ---------------- RoPE on first 32 dims of each head (pairs d, d+16) ----------------
__global__ void k_rope(uint16_t* __restrict__ qb, uint16_t* __restrict__ kb){
  int idx = blockIdx.x*256 + threadIdx.x;      // B*H*T*16
  int d  = idx & 15;
  int t  = (idx >> 4) & (T_-1);
  int bh = idx >> 14;
  size_t base = ((size_t)bh*T_ + t)*HS_;
  float invf = powf(10000.f, -(float)d*(1.f/16.f));
  float ang = (float)t * invf;
  float cs = cosf(ang), sn = sinf(ang);
  float q1 = bf2f(qb[base+d]), q2 = bf2f(qb[base+d+16]);
  qb[base+d]    = f2bf(q1*cs - q2*sn);
  qb[base+d+16] = f2bf(q2*cs + q1*sn);
  float k1 = bf2f(kb[base+d]), k2 = bf2f(kb[base+d+16]);
  kb[base+d]    = f2bf(k1*cs - k2*sn);
  kb[base+d+16] = f2bf(k2*cs + k1*sn);
}

// ---------------- pass A: softmax stats (row max m, denom l) via MFMA QK^T ----------------
__global__ __launch_bounds__(256) void k_stats(const uint16_t* __restrict__ q,
                                               const uint16_t* __restrict__ kmat,
                                               float* __restrict__ sm, float* __restrict__ sl){
  int bh = blockIdx.x, qb = blockIdx.y;
  int lane = threadIdx.x & 63, wid = threadIdx.x >> 6;
  int l16 = lane & 15, lr = lane >> 4;
  int r0 = qb*64 + wid*16;
  const uint16_t* qh = q    + (size_t)bh*T_*HS_;
  const uint16_t* kh = kmat + (size_t)bh*T_*HS_;
  int kq = lr*8;
  bf16x8 a0 = ldb8(qh + (size_t)(r0 + l16)*HS_ + kq);
  bf16x8 a1 = ldb8(qh + (size_t)(r0 + l16)*HS_ + kq + 32);
  float m_[4], l_[4]; int rows[4];
  #pragma unroll
  for (int r=0;r<4;r++){ m_[r] = -1e30f; l_[r] = 0.f; rows[r] = r0 + lr*4 + r; }
  int ktmax = (r0 + 15) >> 4;
  for (int kt = 0; kt <= ktmax; kt++){
    bf16x8 b0 = ldb8(kh + (size_t)(kt*16 + l16)*HS_ + kq);
    bf16x8 b1 = ldb8(kh + (size_t)(kt*16 + l16)*HS_ + kq + 32);
    f32x4 s = {0.f,0.f,0.f,0.f};
    s = mfma16(a0, b0, s);
    s = mfma16(a1, b1, s);
    int kcol = kt*16 + l16;
    #pragma unroll
    for (int r=0;r<4;r++){
      float sv = (kcol <= rows[r]) ? s[r]*0.125f : -1e30f;
      float mx = sv;
      mx = fmaxf(mx, __shfl_xor(mx, 1));
      mx = fmaxf(mx, __shfl_xor(mx, 2));
      mx = fmaxf(mx, __shfl_xor(mx, 4));
      mx = fmaxf(mx, __shfl_xor(mx, 8));
      float mn = fmaxf(m_[r], mx);
      float e = (kcol <= rows[r]) ? expf(sv - mn) : 0.f;
      e += __shfl_xor(e, 1);
      e += __shfl_xor(e, 2);
      e += __shfl_xor(e, 4);
      e += __shfl_xor(e, 8);
      l_[r] = l_[r]*expf(m_[r] - mn) + e;
      m_[r] = mn;
    }
  }
  if (l16 == 0){
    #pragma unroll
    for (int r=0;r<4;r++){
      sm[(size_t)bh*T_ + rows[r]] = m_[r];
      sl[(size_t)bh*T_ + rows[r]] = l_[r];
    }
  }
}

// ---------------- fused attention v2: QK^T -> u -> MFMA head-mix -> PV partials ----------------
// grid (kc=8 chunks of 128 k-cols, qt=32 tiles of 32 q-rows, b=2); 512 thr = 8 waves.
// U LDS: bf16 [p=1024][i=16] (32KB), 16B-blocks XOR-swizzled by p&1.
// C LDS: bf16 [o=16][p=1024 +pad8] (33KB). Mix via mfma_f32_32x32x16_bf16.
__global__ __launch_bounds__(512, 2) void k_attn(
    const uint16_t* __restrict__ q, const uint16_t* __restrict__ kmat,
    const uint16_t* __restrict__ vT,
    const float* __restrict__ sm, const float* __restrict__ sl,
    const float* __restrict__ tw, const float* __restrict__ alpha,
    const float* __restrict__ beta, const float* __restrict__ mixw,
    float* __restrict__ py)
{
  int kc = blockIdx.x, qt = blockIdx.y, b = blockIdx.z;
  if (4*kc > qt) return;
  const int q0 = qt*32, ck0 = kc*128;
  const int nt = min(4, qt - 4*kc + 1);

  __shared__ uint32_t U32[1024*8];        // [p][8 u32 pairs], swizzled
  __shared__ uint16_t Cm[16*1032];        // [o][p], stride 1032 (16B-aligned rows)
  __shared__ float TWL[16*160];

  const int tid = threadIdx.x;
  const int lane = tid & 63;
  const int wid = __builtin_amdgcn_readfirstlane(tid >> 6);
  const int l16 = lane & 15, lr = lane >> 4;
  const int l32 = lane & 31, g32 = lane >> 5;

  const int base = 992 - q0 + ck0;
  for (int i = tid; i < 16*160; i += 512){
    int h = i / 160, t = i - h*160;
    int gi = base + t;
    TWL[i] = (gi <= 1023) ? tw[h*1024 + gi] : 0.f;
  }

  // per-lane stats + Q fragments (register-resident across the k loop)
  float SM[2][2][4], BSL[2][2][4];
  bf16x8 qa[2][2][2];
  #pragma unroll
  for (int h2=0; h2<2; ++h2){
    int h = 2*wid + h2, bh = b*16 + h;
    #pragma unroll
    for (int m=0;m<2;m++){
      #pragma unroll
      for (int r=0;r<4;r++){
        int qq = q0 + m*16 + lr*4 + r;
        SM[h2][m][r]  = sm[(size_t)bh*1024 + qq];
        BSL[h2][m][r] = beta[(size_t)h*1024 + qq] / sl[(size_t)bh*1024 + qq];
      }
      #pragma unroll
      for (int kk=0;kk<2;kk++)
        qa[h2][m][kk] = ldb8(q + ((size_t)bh*1024 + q0 + m*16 + l16)*64 + kk*32 + lr*8);
    }
  }
  // mix-weight B-fragment for 32x32x16 MFMA: Bt[o=l32][i=g32*8+j]
  bf16x8 mwf;
  {
    u16x8 t8;
    #pragma unroll
    for (int j=0;j<8;j++){
      float v = (l32 < 16) ? mixw[l32*16 + g32*8 + j] : 0.f;
      t8[j] = f2bf(v);
    }
    mwf = __builtin_bit_cast(bf16x8, t8);
  }

  const f32x4 z = {0.f,0.f,0.f,0.f};
  f32x4 acc[2][2][4];
  #pragma unroll
  for (int oo=0;oo<2;oo++) for (int m=0;m<2;m++) for (int n=0;n<4;n++) acc[oo][m][n] = z;

  __syncthreads();   // TWL ready

  for (int t = 4*kc; t < 4*kc + nt; ++t){
    const int k0 = t*32;
    const int tt = t - 4*kc;
    // ---- QK^T for this wave's 2 heads ----
    f32x4 s[2][2][2];
    #pragma unroll
    for (int h2=0;h2<2;h2++) for (int m=0;m<2;m++) for (int n=0;n<2;n++) s[h2][m][n] = z;
    #pragma unroll
    for (int h2=0;h2<2;h2++){
      const uint16_t* kh = kmat + ((size_t)(b*16 + 2*wid + h2)*1024 + k0)*64;
      #pragma unroll
      for (int kk=0;kk<2;kk++){
        bf16x8 kb0 = ldb8(kh + (size_t)(l16)*64      + kk*32 + lr*8);
        bf16x8 kb1 = ldb8(kh + (size_t)(16 + l16)*64 + kk*32 + lr*8);
        #pragma unroll
        for (int m=0;m<2;m++){
          s[h2][m][0] = mfma16(qa[h2][m][kk], kb0, s[h2][m][0]);
          s[h2][m][1] = mfma16(qa[h2][m][kk], kb1, s[h2][m][1]);
        }
      }
    }
    // ---- u = exp(s/8 - m)*beta/l*alpha*tw -> packed pair write into U ----
    #pragma unroll
    for (int n=0;n<2;n++){
      int kloc = n*16 + l16;
      int kg = k0 + kloc;
      float al0 = alpha[(2*wid+0)*1024 + kg];
      float al1 = alpha[(2*wid+1)*1024 + kg];
      #pragma unroll
      for (int m=0;m<2;m++){
        #pragma unroll
        for (int r=0;r<4;r++){
          int qloc = m*16 + lr*4 + r;
          bool ok = (kg <= q0 + qloc);
          int twi = 31 - qloc + tt*32 + kloc;
          float u0 = 0.f, u1 = 0.f;
          if (ok){
            u0 = __expf(s[0][m][n][r]*0.125f - SM[0][m][r]) * BSL[0][m][r]
                 * al0 * TWL[(2*wid+0)*160 + twi];
            u1 = __expf(s[1][m][n][r]*0.125f - SM[1][m][r]) * BSL[1][m][r]
                 * al1 * TWL[(2*wid+1)*160 + twi];
          }
          int p = qloc*32 + kloc;
          uint32_t pk = (uint32_t)f2bf(u0) | ((uint32_t)f2bf(u1) << 16);
          U32[p*8 + (((wid>>2) ^ (p&1))<<2) + (wid&3)] = pk;
        }
      }
    }
    __syncthreads();
    // ---- head-mix via 32x32x16 MFMA: C[o][p] = sum_i mw[o][i]*U[p][i] ----
    #pragma unroll
    for (int cc=0; cc<4; ++cc){
      int pbase = (wid*4 + cc)*32;
      int p = pbase + l32;
      int g = g32 ^ (p & 1);
      bf16x8 a = ldb8(reinterpret_cast<const uint16_t*>(U32) + p*16 + g*8);
      f32x16 zz{};
      f32x16 dd = __builtin_amdgcn_mfma_f32_32x32x16_bf16(a, mwf, zz, 0, 0, 0);
      if (l32 < 16){
        int o = l32;
        #pragma unroll
        for (int rg=0; rg<4; ++rg){
          int p0 = pbase + rg*8 + (g32<<2);
          uint32_t w0 = (uint32_t)f2bf(dd[4*rg+0]) | ((uint32_t)f2bf(dd[4*rg+1]) << 16);
          uint32_t w1 = (uint32_t)f2bf(dd[4*rg+2]) | ((uint32_t)f2bf(dd[4*rg+3]) << 16);
          uint2 pk2; pk2.x = w0; pk2.y = w1;
          *reinterpret_cast<uint2*>(Cm + (size_t)o*1032 + p0) = pk2;
        }
      }
    }
    __syncthreads();
    // ---- PV for this wave's 2 output heads ----
    #pragma unroll
    for (int oo=0;oo<2;oo++){
      int o = 2*wid + oo;
      bf16x8 cf0 = ldb8(Cm + (size_t)o*1032 + (l16)*32      + lr*8);
      bf16x8 cf1 = ldb8(Cm + (size_t)o*1032 + (16 + l16)*32 + lr*8);
      const uint16_t* vh = vT + (size_t)(b*16 + o)*64*1024;
      #pragma unroll
      for (int n=0;n<4;n++){
        bf16x8 vf = ldb8(vh + (size_t)(n*16 + l16)*1024 + k0 + lr*8);
        acc[oo][0][n] = mfma16(cf0, vf, acc[oo][0][n]);
        acc[oo][1][n] = mfma16(cf1, vf, acc[oo][1][n]);
      }
    }
    __syncthreads();  // Cm consumed before next tile's mix overwrites; U safe via this + next's post-u barrier
  }

  float* po = py + (((size_t)b*32 + qt)*8 + kc)*32768;
  #pragma unroll
  for (int oo=0;oo<2;oo++){
    int o = 2*wid + oo;
    #pragma unroll
    for (int m=0;m<2;m++)
      #pragma unroll
      for (int n=0;n<4;n++)
        #pragma unroll
        for (int r=0;r<4;r++){
          int qloc = m*16 + lr*4 + r;
          po[((size_t)o*32 + qloc)*64 + n*16 + l16] = acc[oo][m][n][r];
        }
  }
}

// ---------------- reduce partials -> ybuf bf16 [B,T,C] ----------------
__global__ void k_yred(const float* __restrict__ py, uint16_t* __restrict__ y){
  int flat = blockIdx.x*256 + threadIdx.x;   // 0..524287, one float4 each
  int d4 = flat & 15, o = (flat>>4)&15, ql = (flat>>8)&31, qt = (flat>>13)&31, b = flat>>18;
  int nch = (qt>>2) + 1;
  const float* p0 = py + (((size_t)b*32 + qt)*8)*32768 + ((size_t)o*32 + ql)*64 + d4*4;
  float4 s = {0.f,0.f,0.f,0.f};
  for (int kc=0; kc<nch; kc++){
    float4 v = *reinterpret_cast<const float4*>(p0 + (size_t)kc*32768);
    s.x += v.x; s.y += v.y; s.z += v.z; s.w += v.w;
  }
  int t = qt*32 + ql;
  uint16_t* yp = y + ((size_t)(b*1024 + t))*1024 + o*64 + d4*4;
  yp[0] = f2bf(s.x); yp[1] = f2bf(s.y); yp[2] = f2bf(s.z); yp[3] = f2bf(s.w);
}

// ---------------- GEGLU elementwise: g = gelu_exact(kk) * vv ----------------
__global__ void k_geglu(const uint16_t* __restrict__ kk, const uint16_t* __restrict__ vv,
                        uint16_t* __restrict__ g){
  size_t i = ((size_t)blockIdx.x*256 + threadIdx.x)*8;
  u16x8 a = *reinterpret_cast<const u16x8*>(kk + i);
  u16x8 b = *reinterpret_cast<const u16x8*>(vv + i);
  u16x8 o;
  #pragma unroll
  for (int e=0;e<8;e++){
    float xv = bf2f(a[e]);
    float gl = 0.5f*xv*(1.f + erff(xv*0.70710678118f));
    o[e] = f2bf(gl * bf2f(b[e]));
  }
  *reinterpret_cast<u16x8*>(g + i) = o;
}

// ---------------- host ----------------
extern "C" void kernel_launch(void* const* d_in, const int* in_sizes, int n_in,
                              void* d_out, int out_size, void* d_ws, size_t ws_size,
                              hipStream_t stream)
{
  const float* x      = (const float*)d_in[0];
  const float* ln1w   = (const float*)d_in[1];
  const float* ln1b   = (const float*)d_in[2];
  const float* ln2w   = (const float*)d_in[3];
  const float* ln2b   = (const float*)d_in[4];
  const float* Wq     = (const float*)d_in[5];
  const float* bq     = (const float*)d_in[6];
  const float* Wk     = (const float*)d_in[7];
  const float* bk     = (const float*)d_in[8];
  const float* Wv     = (const float*)d_in[9];
  const float* bv     = (const float*)d_in[10];
  const float* Wo     = (const float*)d_in[11];
  const float* bo     = (const float*)d_in[12];
  const float* tw     = (const float*)d_in[13];
  const float* talpha = (const float*)d_in[14];
  const float* tbeta  = (const float*)d_in[15];
  const float* tgamma = (const float*)d_in[16];
  const float* mixw   = (const float*)d_in[17];
  const float* Wkg    = (const float*)d_in[18];
  const float* bkg    = (const float*)d_in[19];
  const float* Wvg    = (const float*)d_in[20];
  const float* bvg    = (const float*)d_in[21];
  const float* Wwg    = (const float*)d_in[22];
  const float* bwg    = (const float*)d_in[23];

  char* ws = (char*)d_ws;
  size_t off = 0;
  auto alloc = [&](size_t bytes)->char*{
    char* p = ws + off; off += (bytes + 255) & ~(size_t)255; return p;
  };
  uint16_t* WqT  = (uint16_t*)alloc((size_t)C_*C_*2);
  uint16_t* WkT  = (uint16_t*)alloc((size_t)C_*C_*2);
  uint16_t* WvT  = (uint16_t*)alloc((size_t)C_*C_*2);
  uint16_t* WoT  = (uint16_t*)alloc((size_t)C_*C_*2);
  uint16_t* WkgT = (uint16_t*)alloc((size_t)FFN_*C_*2);
  uint16_t* WvgT = (uint16_t*)alloc((size_t)FFN_*C_*2);
  uint16_t* WwgT = (uint16_t*)alloc((size_t)C_*FFN_*2);
  uint16_t* xs   = (uint16_t*)alloc((size_t)B_*T_*C_*2);
  uint16_t* qbuf = (uint16_t*)alloc((size_t)B_*T_*C_*2);
  uint16_t* kbuf = (uint16_t*)alloc((size_t)B_*T_*C_*2);
  uint16_t* vT   = (uint16_t*)alloc((size_t)B_*T_*C_*2);
  float*    sm   = (float*)alloc((size_t)B_*H_*T_*4);
  float*    sl   = (float*)alloc((size_t)B_*H_*T_*4);
  uint16_t* ybuf = (uint16_t*)alloc((size_t)B_*T_*C_*2);
  float*    x1   = (float*)alloc((size_t)B_*T_*C_*4);
  // 64 MB region: attention partials, then reused for FFN intermediates
  char*     region = alloc((size_t)2*32*8*32768*4);      // 512 * 32768 f32 = 64 MB
  float*    py  = (float*)region;
  uint16_t* kkb = (uint16_t*)region;
  uint16_t* vvb = kkb + (size_t)2048*3072;
  uint16_t* gb  = kkb + (size_t)2*2048*3072;

  if (off > ws_size){
    fprintf(stderr, "kernel_launch: ws too small (%zu needed, %zu given)\n", off, ws_size);
    return;
  }

  dim3 blk(256);
  dim3 tblk(32,8);
  k_transpose<<<dim3(32,32), tblk, 0, stream>>>(Wq,  WqT,  C_,  C_);
  k_transpose<<<dim3(32,32), tblk, 0, stream>>>(Wk,  WkT,  C_,  C_);
  k_transpose<<<dim3(32,32), tblk, 0, stream>>>(Wv,  WvT,  C_,  C_);
  k_transpose<<<dim3(32,32), tblk, 0, stream>>>(Wo,  WoT,  C_,  C_);
  k_transpose<<<dim3(96,32), tblk, 0, stream>>>(Wkg, WkgT, C_,  FFN_);
  k_transpose<<<dim3(96,32), tblk, 0, stream>>>(Wvg, WvgT, C_,  FFN_);
  k_transpose<<<dim3(32,96), tblk, 0, stream>>>(Wwg, WwgT, FFN_, C_);

  k_ln<1><<<B_*T_, blk, 0, stream>>>(x, ln1w, ln1b, xs);

  k_gemm2<EPI_QK,64><<<dim3(16,16), blk, 0, stream>>>(xs, WqT, bq, qbuf, 2048, 1024, 1024, nullptr, nullptr);
  k_gemm2<EPI_QK,64><<<dim3(16,16), blk, 0, stream>>>(xs, WkT, bk, kbuf, 2048, 1024, 1024, nullptr, nullptr);
  k_gemm2<EPI_VT,64><<<dim3(16,16), blk, 0, stream>>>(xs, WvT, bv, vT,   2048, 1024, 1024, nullptr, nullptr);

  k_rope<<<2048, blk, 0, stream>>>(qbuf, kbuf);
  k_stats<<<dim3(B_*H_, T_/64), blk, 0, stream>>>(qbuf, kbuf, sm, sl);
  k_attn<<<dim3(8,32,B_), dim3(512), 0, stream>>>(qbuf, kbuf, vT, sm, sl,
                                                  tw, talpha, tbeta, mixw, py);
  k_yred<<<2048, blk, 0, stream>>>(py, ybuf);

  k_gemm2<EPI_WO,64><<<dim3(16,16), blk, 0, stream>>>(ybuf, WoT, bo, x1, 2048, 1024, 1024, tgamma, x);

  k_ln<0><<<B_*T_, blk, 0, stream>>>(x1, ln2w, ln2b, xs);

  k_gemm2<EPI_BF16,128><<<dim3(24,16), blk, 0, stream>>>(xs, WkgT, bkg, kkb, 2048, 3072, 1024, nullptr, nullptr);
  k_gemm2<EPI_BF16,128><<<dim3(24,16), blk, 0, stream>>>(xs, WvgT, bvg, vvb, 2048, 3072, 1024, nullptr, nullptr);
  k_geglu<<<(2048*3072/8)/256, blk, 0, stream>>>(kkb, vvb, gb);
  k_gemm2<EPI_FFN2,64><<<dim3(16,16), blk, 0, stream>>>(gb, WwgT, bwg, d_out, 2048, 1024, 3072, x1, nullptr);
}

// Round 4
// 344.053 us; speedup vs baseline: 1.5321x; 1.1730x over previous
//
#include <hip/hip_runtime.h>
#include <cstdint>
#include <cstddef>
#include <cstdio>

// ---------------- constants ----------------
#define B_   2
#define T_   1024
#define C_   1024
#define H_   16
#define HS_  64
#define FFN_ 3072

typedef __bf16   bf16x8 __attribute__((ext_vector_type(8)));
typedef float    f32x4  __attribute__((ext_vector_type(4)));
typedef float    f32x16 __attribute__((ext_vector_type(16)));
typedef uint16_t u16x8  __attribute__((ext_vector_type(8)));

__device__ __forceinline__ uint16_t f2bf(float f){
  uint32_t u = __float_as_uint(f);
  u += 0x7FFFu + ((u >> 16) & 1u);          // RNE
  return (uint16_t)(u >> 16);
}
__device__ __forceinline__ float bf2f(uint16_t h){
  return __uint_as_float(((uint32_t)h) << 16);
}
__device__ __forceinline__ bf16x8 ldb8(const uint16_t* p){
  return __builtin_bit_cast(bf16x8, *reinterpret_cast<const u16x8*>(p));
}
__device__ __forceinline__ f32x4 mfma16(bf16x8 a, bf16x8 b, f32x4 c){
  return __builtin_amdgcn_mfma_f32_16x16x32_bf16(a, b, c, 0, 0, 0);
}

// async global->LDS, 16B per lane
typedef __attribute__((address_space(1))) const uint32_t* gas_t;
typedef __attribute__((address_space(3))) uint32_t* las_t;
__device__ __forceinline__ void gl_lds16(const uint16_t* g, uint16_t* l){
  __builtin_amdgcn_global_load_lds((gas_t)g, (las_t)l, 16, 0, 0);
}

// ---------------- transpose f32 [R][C] -> bf16 [C][R] ----------------
__global__ __launch_bounds__(256) void k_transpose(const float* __restrict__ in,
                                                   uint16_t* __restrict__ out,
                                                   int R, int Cc){
  __shared__ float tile[32][33];
  int c0 = blockIdx.x*32, r0 = blockIdx.y*32;
  int tx = threadIdx.x, ty = threadIdx.y;   // (32,8)
  #pragma unroll
  for (int i=0;i<4;i++) tile[ty+i*8][tx] = in[(size_t)(r0+ty+i*8)*Cc + c0+tx];
  __syncthreads();
  #pragma unroll
  for (int i=0;i<4;i++) out[(size_t)(c0+ty+i*8)*R + r0+tx] = f2bf(tile[tx][ty+i*8]);
}

// ---------------- LayerNorm (+optional time-shift-half scatter) ----------------
template<int SHIFT>
__global__ __launch_bounds__(256) void k_ln(const float* __restrict__ in,
                                            const float* __restrict__ w,
                                            const float* __restrict__ bia,
                                            uint16_t* __restrict__ out){
  int row = blockIdx.x;                 // b*T + t
  int t = row & (T_-1);
  const float* xr = in + (size_t)row*C_;
  float4 v = reinterpret_cast<const float4*>(xr)[threadIdx.x];
  float s  = v.x+v.y+v.z+v.w;
  float s2 = v.x*v.x+v.y*v.y+v.z*v.z+v.w*v.w;
  #pragma unroll
  for (int o=1;o<64;o<<=1){ s += __shfl_xor(s,o); s2 += __shfl_xor(s2,o); }
  __shared__ float red[8];
  int lane = threadIdx.x & 63, wid = threadIdx.x >> 6;
  if (lane == 0){ red[wid] = s; red[4+wid] = s2; }
  __syncthreads();
  s  = red[0]+red[1]+red[2]+red[3];
  s2 = red[4]+red[5]+red[6]+red[7];
  float mean = s * (1.f/1024.f);
  float var  = s2 * (1.f/1024.f) - mean*mean;
  float rs   = rsqrtf(var + 1e-5f);
  float vals[4] = {v.x, v.y, v.z, v.w};
  #pragma unroll
  for (int j=0;j<4;j++){
    int cc = threadIdx.x*4 + j;
    float o_ = (vals[j]-mean)*rs*w[cc] + bia[cc];
    uint16_t ob = f2bf(o_);
    if (SHIFT){
      if (cc < 512){
        if (t < T_-1) out[(size_t)(row+1)*C_ + cc] = ob;
        if (t == 0)   out[(size_t)row*C_ + cc] = 0;
      } else {
        out[(size_t)row*C_ + cc] = ob;
      }
    } else {
      out[(size_t)row*C_ + cc] = ob;
    }
  }
}

// ---------------- MFMA GEMM v2: C = A[M][K] * Bt[N][K]^T (+bias) ----------------
// tile 128 x BN, BK=32, 4 waves (2x2), global_load_lds staging (m97 structure)
enum { EPI_QK=0, EPI_VT=1, EPI_WO=2, EPI_BF16=3, EPI_FFN2=4 };

template<int EPI, int BN>
__global__ __launch_bounds__(256) void k_gemm2(
    const uint16_t* __restrict__ A, const uint16_t* __restrict__ Bt,
    const float* __restrict__ bias, void* __restrict__ outp,
    int M, int N, int K,
    const float* __restrict__ aux0, const float* __restrict__ aux1)
{
  __shared__ uint16_t As[128*32];
  __shared__ uint16_t Bs[BN*32];
  const int m0 = blockIdx.y*128, n0 = blockIdx.x*BN;
  const int tid = threadIdx.x;
  const int lane = tid & 63, wid = tid >> 6;
  const int wy = wid >> 1, wx = wid & 1;
  const int l16 = lane & 15, lr = lane >> 4;
  const int WN = BN/2;            // wave cols
  const int NW = BN/32;           // b-frags per wave
  const f32x4 z = {0.f,0.f,0.f,0.f};
  f32x4 acc[4][NW];
  #pragma unroll
  for (int m=0;m<4;m++)
    #pragma unroll
    for (int n=0;n<NW;n++) acc[m][n] = z;
  const int srow = tid >> 2, scol = (tid & 3)*8;
  for (int k0 = 0; k0 < K; k0 += 32){
    gl_lds16(A + (size_t)(m0 + srow)*K      + k0 + scol, As + tid*8);
    gl_lds16(A + (size_t)(m0 + 64 + srow)*K + k0 + scol, As + 2048 + tid*8);
    gl_lds16(Bt + (size_t)(n0 + srow)*K     + k0 + scol, Bs + tid*8);
    if constexpr (BN == 128)
      gl_lds16(Bt + (size_t)(n0 + 64 + srow)*K + k0 + scol, Bs + 2048 + tid*8);
    __syncthreads();
    bf16x8 af[4], bfr[NW];
    #pragma unroll
    for (int m=0;m<4;m++) af[m] = ldb8(As + (wy*64 + m*16 + l16)*32 + lr*8);
    #pragma unroll
    for (int n=0;n<NW;n++) bfr[n] = ldb8(Bs + (wx*WN + n*16 + l16)*32 + lr*8);
    #pragma unroll
    for (int m=0;m<4;m++)
      #pragma unroll
      for (int n=0;n<NW;n++) acc[m][n] = mfma16(af[m], bfr[n], acc[m][n]);
    __syncthreads();
  }
  #pragma unroll
  for (int m=0;m<4;m++){
    #pragma unroll
    for (int n=0;n<NW;n++){
      int col = n0 + wx*WN + n*16 + l16;
      float bc_ = bias ? bias[col] : 0.f;
      #pragma unroll
      for (int r=0;r<4;r++){
        int row = m0 + wy*64 + m*16 + lr*4 + r;
        float v = acc[m][n][r] + bc_;
        if constexpr (EPI == EPI_QK){
          int bb = row >> 10, t = row & (T_-1), h = col >> 6, d = col & 63;
          ((uint16_t*)outp)[((((size_t)bb*H_ + h)*T_ + t)<<6) + d] = f2bf(v);
        } else if constexpr (EPI == EPI_VT){
          int bb = row >> 10, t = row & (T_-1), h = col >> 6, d = col & 63;
          ((uint16_t*)outp)[(((size_t)bb*H_ + h)*HS_ + d)*T_ + t] = f2bf(v);
        } else if constexpr (EPI == EPI_WO){
          int t = row & (T_-1);
          ((float*)outp)[(size_t)row*N + col] = aux1[(size_t)row*N + col] + v*aux0[t];
        } else if constexpr (EPI == EPI_BF16){
          ((uint16_t*)outp)[(size_t)row*N + col] = f2bf(v);
        } else { // EPI_FFN2
          ((float*)outp)[(size_t)row*N + col] = aux0[(size_t)row*N + col] + v;
        }
      }
    }
  }
}

// ---------------- RoPE on first 32 dims of each head (pairs d, d+16) ----------------
__global__ void k_rope(uint16_t* __restrict__ qb, uint16_t* __restrict__ kb){
  int idx = blockIdx.x*256 + threadIdx.x;      // B*H*T*16
  int d  = idx & 15;
  int t  = (idx >> 4) & (T_-1);
  int bh = idx >> 14;
  size_t base = ((size_t)bh*T_ + t)*HS_;
  float invf = powf(10000.f, -(float)d*(1.f/16.f));
  float ang = (float)t * invf;
  float cs = cosf(ang), sn = sinf(ang);
  float q1 = bf2f(qb[base+d]), q2 = bf2f(qb[base+d+16]);
  qb[base+d]    = f2bf(q1*cs - q2*sn);
  qb[base+d+16] = f2bf(q2*cs + q1*sn);
  float k1 = bf2f(kb[base+d]), k2 = bf2f(kb[base+d+16]);
  kb[base+d]    = f2bf(k1*cs - k2*sn);
  kb[base+d+16] = f2bf(k2*cs + k1*sn);
}

// ---------------- pass A: softmax stats via per-lane ONLINE accumulation ----------------
// No shuffles in the k-loop; 16-lane (m,l) log-sum-exp merge once at the end.
__global__ __launch_bounds__(256) void k_stats(const uint16_t* __restrict__ q,
                                               const uint16_t* __restrict__ kmat,
                                               float* __restrict__ sm, float* __restrict__ sl){
  int bh = blockIdx.x, qb = blockIdx.y;
  int lane = threadIdx.x & 63, wid = threadIdx.x >> 6;
  int l16 = lane & 15, lr = lane >> 4;
  int r0 = qb*64 + wid*16;
  const uint16_t* qh = q    + (size_t)bh*T_*HS_;
  const uint16_t* kh = kmat + (size_t)bh*T_*HS_;
  int kq = lr*8;
  bf16x8 a0 = ldb8(qh + (size_t)(r0 + l16)*HS_ + kq);
  bf16x8 a1 = ldb8(qh + (size_t)(r0 + l16)*HS_ + kq + 32);
  float m_[4], l_[4]; int rows[4];
  #pragma unroll
  for (int r=0;r<4;r++){ m_[r] = -1e30f; l_[r] = 0.f; rows[r] = r0 + lr*4 + r; }
  int ktmax = (r0 + 15) >> 4;
  for (int kt = 0; kt <= ktmax; kt++){
    bf16x8 b0 = ldb8(kh + (size_t)(kt*16 + l16)*HS_ + kq);
    bf16x8 b1 = ldb8(kh + (size_t)(kt*16 + l16)*HS_ + kq + 32);
    f32x4 s = {0.f,0.f,0.f,0.f};
    s = mfma16(a0, b0, s);
    s = mfma16(a1, b1, s);
    int kcol = kt*16 + l16;
    #pragma unroll
    for (int r=0;r<4;r++){
      // per-lane online update, no cross-lane ops
      float sv = (kcol <= rows[r]) ? s[r]*0.125f : -3.0e38f;
      float mn = fmaxf(m_[r], sv);
      l_[r] = l_[r]*__expf(m_[r] - mn) + __expf(sv - mn);
      m_[r] = mn;
    }
  }
  // merge the 16 per-lane partials of each row (lanes l16=0..15 share lr)
  #pragma unroll
  for (int o=1;o<16;o<<=1){
    #pragma unroll
    for (int r=0;r<4;r++){
      float mo = __shfl_xor(m_[r], o);
      float lo = __shfl_xor(l_[r], o);
      float mn = fmaxf(m_[r], mo);
      l_[r] = l_[r]*__expf(m_[r] - mn) + lo*__expf(mo - mn);
      m_[r] = mn;
    }
  }
  if (l16 == 0){
    #pragma unroll
    for (int r=0;r<4;r++){
      sm[(size_t)bh*T_ + rows[r]] = m_[r];
      sl[(size_t)bh*T_ + rows[r]] = l_[r];
    }
  }
}

// ---------------- fused attention v2: QK^T -> u -> MFMA head-mix -> PV partials ----------------
// grid (kc=8 chunks of 128 k-cols, qt=32 tiles of 32 q-rows, b=2); 512 thr = 8 waves.
// U LDS: bf16 [p=1024][i=16] (32KB), 16B-blocks XOR-swizzled by p&1.
// C LDS: bf16 [o=16][p=1024 +pad8] (33KB). Mix via mfma_f32_32x32x16_bf16.
__global__ __launch_bounds__(512, 2) void k_attn(
    const uint16_t* __restrict__ q, const uint16_t* __restrict__ kmat,
    const uint16_t* __restrict__ vT,
    const float* __restrict__ sm, const float* __restrict__ sl,
    const float* __restrict__ tw, const float* __restrict__ alpha,
    const float* __restrict__ beta, const float* __restrict__ mixw,
    float* __restrict__ py)
{
  int kc = blockIdx.x, qt = blockIdx.y, b = blockIdx.z;
  if (4*kc > qt) return;
  const int q0 = qt*32, ck0 = kc*128;
  const int nt = min(4, qt - 4*kc + 1);

  __shared__ uint32_t U32[1024*8];        // [p][8 u32 pairs], swizzled
  __shared__ uint16_t Cm[16*1032];        // [o][p], stride 1032 (16B-aligned rows)
  __shared__ float TWL[16*160];

  const int tid = threadIdx.x;
  const int lane = tid & 63;
  const int wid = __builtin_amdgcn_readfirstlane(tid >> 6);
  const int l16 = lane & 15, lr = lane >> 4;
  const int l32 = lane & 31, g32 = lane >> 5;

  const int base = 992 - q0 + ck0;
  for (int i = tid; i < 16*160; i += 512){
    int h = i / 160, t = i - h*160;
    int gi = base + t;
    TWL[i] = (gi <= 1023) ? tw[h*1024 + gi] : 0.f;
  }

  // per-lane stats + Q fragments (register-resident across the k loop)
  float SM[2][2][4], BSL[2][2][4];
  bf16x8 qa[2][2][2];
  #pragma unroll
  for (int h2=0; h2<2; ++h2){
    int h = 2*wid + h2, bh = b*16 + h;
    #pragma unroll
    for (int m=0;m<2;m++){
      #pragma unroll
      for (int r=0;r<4;r++){
        int qq = q0 + m*16 + lr*4 + r;
        SM[h2][m][r]  = sm[(size_t)bh*1024 + qq];
        BSL[h2][m][r] = beta[(size_t)h*1024 + qq] / sl[(size_t)bh*1024 + qq];
      }
      #pragma unroll
      for (int kk=0;kk<2;kk++)
        qa[h2][m][kk] = ldb8(q + ((size_t)bh*1024 + q0 + m*16 + l16)*64 + kk*32 + lr*8);
    }
  }
  // mix-weight B-fragment for 32x32x16 MFMA: Bt[o=l32][i=g32*8+j]
  bf16x8 mwf;
  {
    u16x8 t8;
    #pragma unroll
    for (int j=0;j<8;j++){
      float v = (l32 < 16) ? mixw[l32*16 + g32*8 + j] : 0.f;
      t8[j] = f2bf(v);
    }
    mwf = __builtin_bit_cast(bf16x8, t8);
  }

  const f32x4 z = {0.f,0.f,0.f,0.f};
  f32x4 acc[2][2][4];
  #pragma unroll
  for (int oo=0;oo<2;oo++) for (int m=0;m<2;m++) for (int n=0;n<4;n++) acc[oo][m][n] = z;

  __syncthreads();   // TWL ready

  for (int t = 4*kc; t < 4*kc + nt; ++t){
    const int k0 = t*32;
    const int tt = t - 4*kc;
    // ---- QK^T for this wave's 2 heads ----
    f32x4 s[2][2][2];
    #pragma unroll
    for (int h2=0;h2<2;h2++) for (int m=0;m<2;m++) for (int n=0;n<2;n++) s[h2][m][n] = z;
    #pragma unroll
    for (int h2=0;h2<2;h2++){
      const uint16_t* kh = kmat + ((size_t)(b*16 + 2*wid + h2)*1024 + k0)*64;
      #pragma unroll
      for (int kk=0;kk<2;kk++){
        bf16x8 kb0 = ldb8(kh + (size_t)(l16)*64      + kk*32 + lr*8);
        bf16x8 kb1 = ldb8(kh + (size_t)(16 + l16)*64 + kk*32 + lr*8);
        #pragma unroll
        for (int m=0;m<2;m++){
          s[h2][m][0] = mfma16(qa[h2][m][kk], kb0, s[h2][m][0]);
          s[h2][m][1] = mfma16(qa[h2][m][kk], kb1, s[h2][m][1]);
        }
      }
    }
    // ---- u = exp(s/8 - m)*beta/l*alpha*tw -> packed pair write into U ----
    #pragma unroll
    for (int n=0;n<2;n++){
      int kloc = n*16 + l16;
      int kg = k0 + kloc;
      float al0 = alpha[(2*wid+0)*1024 + kg];
      float al1 = alpha[(2*wid+1)*1024 + kg];
      #pragma unroll
      for (int m=0;m<2;m++){
        #pragma unroll
        for (int r=0;r<4;r++){
          int qloc = m*16 + lr*4 + r;
          bool ok = (kg <= q0 + qloc);
          int twi = 31 - qloc + tt*32 + kloc;
          float u0 = 0.f, u1 = 0.f;
          if (ok){
            u0 = __expf(s[0][m][n][r]*0.125f - SM[0][m][r]) * BSL[0][m][r]
                 * al0 * TWL[(2*wid+0)*160 + twi];
            u1 = __expf(s[1][m][n][r]*0.125f - SM[1][m][r]) * BSL[1][m][r]
                 * al1 * TWL[(2*wid+1)*160 + twi];
          }
          int p = qloc*32 + kloc;
          uint32_t pk = (uint32_t)f2bf(u0) | ((uint32_t)f2bf(u1) << 16);
          U32[p*8 + (((wid>>2) ^ (p&1))<<2) + (wid&3)] = pk;
        }
      }
    }
    __syncthreads();
    // ---- head-mix via 32x32x16 MFMA: C[o][p] = sum_i mw[o][i]*U[p][i] ----
    #pragma unroll
    for (int cc=0; cc<4; ++cc){
      int pbase = (wid*4 + cc)*32;
      int p = pbase + l32;
      int g = g32 ^ (p & 1);
      bf16x8 a = ldb8(reinterpret_cast<const uint16_t*>(U32) + p*16 + g*8);
      f32x16 zz{};
      f32x16 dd = __builtin_amdgcn_mfma_f32_32x32x16_bf16(a, mwf, zz, 0, 0, 0);
      if (l32 < 16){
        int o = l32;
        #pragma unroll
        for (int rg=0; rg<4; ++rg){
          int p0 = pbase + rg*8 + (g32<<2);
          uint32_t w0 = (uint32_t)f2bf(dd[4*rg+0]) | ((uint32_t)f2bf(dd[4*rg+1]) << 16);
          uint32_t w1 = (uint32_t)f2bf(dd[4*rg+2]) | ((uint32_t)f2bf(dd[4*rg+3]) << 16);
          uint2 pk2; pk2.x = w0; pk2.y = w1;
          *reinterpret_cast<uint2*>(Cm + (size_t)o*1032 + p0) = pk2;
        }
      }
    }
    __syncthreads();
    // ---- PV for this wave's 2 output heads ----
    #pragma unroll
    for (int oo=0;oo<2;oo++){
      int o = 2*wid + oo;
      bf16x8 cf0 = ldb8(Cm + (size_t)o*1032 + (l16)*32      + lr*8);
      bf16x8 cf1 = ldb8(Cm + (size_t)o*1032 + (16 + l16)*32 + lr*8);
      const uint16_t* vh = vT + (size_t)(b*16 + o)*64*1024;
      #pragma unroll
      for (int n=0;n<4;n++){
        bf16x8 vf = ldb8(vh + (size_t)(n*16 + l16)*1024 + k0 + lr*8);
        acc[oo][0][n] = mfma16(cf0, vf, acc[oo][0][n]);
        acc[oo][1][n] = mfma16(cf1, vf, acc[oo][1][n]);
      }
    }
    __syncthreads();  // Cm consumed before next tile's mix overwrites; U safe via this + next's post-u barrier
  }

  float* po = py + (((size_t)b*32 + qt)*8 + kc)*32768;
  #pragma unroll
  for (int oo=0;oo<2;oo++){
    int o = 2*wid + oo;
    #pragma unroll
    for (int m=0;m<2;m++)
      #pragma unroll
      for (int n=0;n<4;n++)
        #pragma unroll
        for (int r=0;r<4;r++){
          int qloc = m*16 + lr*4 + r;
          po[((size_t)o*32 + qloc)*64 + n*16 + l16] = acc[oo][m][n][r];
        }
  }
}

// ---------------- reduce partials -> ybuf bf16 [B,T,C] ----------------
__global__ void k_yred(const float* __restrict__ py, uint16_t* __restrict__ y){
  int flat = blockIdx.x*256 + threadIdx.x;   // 0..524287, one float4 each
  int d4 = flat & 15, o = (flat>>4)&15, ql = (flat>>8)&31, qt = (flat>>13)&31, b = flat>>18;
  int nch = (qt>>2) + 1;
  const float* p0 = py + (((size_t)b*32 + qt)*8)*32768 + ((size_t)o*32 + ql)*64 + d4*4;
  float4 s = {0.f,0.f,0.f,0.f};
  for (int kc=0; kc<nch; kc++){
    float4 v = *reinterpret_cast<const float4*>(p0 + (size_t)kc*32768);
    s.x += v.x; s.y += v.y; s.z += v.z; s.w += v.w;
  }
  int t = qt*32 + ql;
  uint16_t* yp = y + ((size_t)(b*1024 + t))*1024 + o*64 + d4*4;
  yp[0] = f2bf(s.x); yp[1] = f2bf(s.y); yp[2] = f2bf(s.z); yp[3] = f2bf(s.w);
}

// ---------------- GEGLU elementwise: g = gelu_exact(kk) * vv ----------------
__global__ void k_geglu(const uint16_t* __restrict__ kk, const uint16_t* __restrict__ vv,
                        uint16_t* __restrict__ g){
  size_t i = ((size_t)blockIdx.x*256 + threadIdx.x)*8;
  u16x8 a = *reinterpret_cast<const u16x8*>(kk + i);
  u16x8 b = *reinterpret_cast<const u16x8*>(vv + i);
  u16x8 o;
  #pragma unroll
  for (int e=0;e<8;e++){
    float xv = bf2f(a[e]);
    float gl = 0.5f*xv*(1.f + erff(xv*0.70710678118f));
    o[e] = f2bf(gl * bf2f(b[e]));
  }
  *reinterpret_cast<u16x8*>(g + i) = o;
}

// ---------------- host ----------------
extern "C" void kernel_launch(void* const* d_in, const int* in_sizes, int n_in,
                              void* d_out, int out_size, void* d_ws, size_t ws_size,
                              hipStream_t stream)
{
  const float* x      = (const float*)d_in[0];
  const float* ln1w   = (const float*)d_in[1];
  const float* ln1b   = (const float*)d_in[2];
  const float* ln2w   = (const float*)d_in[3];
  const float* ln2b   = (const float*)d_in[4];
  const float* Wq     = (const float*)d_in[5];
  const float* bq     = (const float*)d_in[6];
  const float* Wk     = (const float*)d_in[7];
  const float* bk     = (const float*)d_in[8];
  const float* Wv     = (const float*)d_in[9];
  const float* bv     = (const float*)d_in[10];
  const float* Wo     = (const float*)d_in[11];
  const float* bo     = (const float*)d_in[12];
  const float* tw     = (const float*)d_in[13];
  const float* talpha = (const float*)d_in[14];
  const float* tbeta  = (const float*)d_in[15];
  const float* tgamma = (const float*)d_in[16];
  const float* mixw   = (const float*)d_in[17];
  const float* Wkg    = (const float*)d_in[18];
  const float* bkg    = (const float*)d_in[19];
  const float* Wvg    = (const float*)d_in[20];
  const float* bvg    = (const float*)d_in[21];
  const float* Wwg    = (const float*)d_in[22];
  const float* bwg    = (const float*)d_in[23];

  char* ws = (char*)d_ws;
  size_t off = 0;
  auto alloc = [&](size_t bytes)->char*{
    char* p = ws + off; off += (bytes + 255) & ~(size_t)255; return p;
  };
  uint16_t* WqT  = (uint16_t*)alloc((size_t)C_*C_*2);
  uint16_t* WkT  = (uint16_t*)alloc((size_t)C_*C_*2);
  uint16_t* WvT  = (uint16_t*)alloc((size_t)C_*C_*2);
  uint16_t* WoT  = (uint16_t*)alloc((size_t)C_*C_*2);
  uint16_t* WkgT = (uint16_t*)alloc((size_t)FFN_*C_*2);
  uint16_t* WvgT = (uint16_t*)alloc((size_t)FFN_*C_*2);
  uint16_t* WwgT = (uint16_t*)alloc((size_t)C_*FFN_*2);
  uint16_t* xs   = (uint16_t*)alloc((size_t)B_*T_*C_*2);
  uint16_t* qbuf = (uint16_t*)alloc((size_t)B_*T_*C_*2);
  uint16_t* kbuf = (uint16_t*)alloc((size_t)B_*T_*C_*2);
  uint16_t* vT   = (uint16_t*)alloc((size_t)B_*T_*C_*2);
  float*    sm   = (float*)alloc((size_t)B_*H_*T_*4);
  float*    sl   = (float*)alloc((size_t)B_*H_*T_*4);
  uint16_t* ybuf = (uint16_t*)alloc((size_t)B_*T_*C_*2);
  float*    x1   = (float*)alloc((size_t)B_*T_*C_*4);
  // 64 MB region: attention partials, then reused for FFN intermediates
  char*     region = alloc((size_t)2*32*8*32768*4);      // 512 * 32768 f32 = 64 MB
  float*    py  = (float*)region;
  uint16_t* kkb = (uint16_t*)region;
  uint16_t* vvb = kkb + (size_t)2048*3072;
  uint16_t* gb  = kkb + (size_t)2*2048*3072;

  if (off > ws_size){
    fprintf(stderr, "kernel_launch: ws too small (%zu needed, %zu given)\n", off, ws_size);
    return;
  }

  dim3 blk(256);
  dim3 tblk(32,8);
  k_transpose<<<dim3(32,32), tblk, 0, stream>>>(Wq,  WqT,  C_,  C_);
  k_transpose<<<dim3(32,32), tblk, 0, stream>>>(Wk,  WkT,  C_,  C_);
  k_transpose<<<dim3(32,32), tblk, 0, stream>>>(Wv,  WvT,  C_,  C_);
  k_transpose<<<dim3(32,32), tblk, 0, stream>>>(Wo,  WoT,  C_,  C_);
  k_transpose<<<dim3(96,32), tblk, 0, stream>>>(Wkg, WkgT, C_,  FFN_);
  k_transpose<<<dim3(96,32), tblk, 0, stream>>>(Wvg, WvgT, C_,  FFN_);
  k_transpose<<<dim3(32,96), tblk, 0, stream>>>(Wwg, WwgT, FFN_, C_);

  k_ln<1><<<B_*T_, blk, 0, stream>>>(x, ln1w, ln1b, xs);

  k_gemm2<EPI_QK,64><<<dim3(16,16), blk, 0, stream>>>(xs, WqT, bq, qbuf, 2048, 1024, 1024, nullptr, nullptr);
  k_gemm2<EPI_QK,64><<<dim3(16,16), blk, 0, stream>>>(xs, WkT, bk, kbuf, 2048, 1024, 1024, nullptr, nullptr);
  k_gemm2<EPI_VT,64><<<dim3(16,16), blk, 0, stream>>>(xs, WvT, bv, vT,   2048, 1024, 1024, nullptr, nullptr);

  k_rope<<<2048, blk, 0, stream>>>(qbuf, kbuf);
  k_stats<<<dim3(B_*H_, T_/64), blk, 0, stream>>>(qbuf, kbuf, sm, sl);
  k_attn<<<dim3(8,32,B_), dim3(512), 0, stream>>>(qbuf, kbuf, vT, sm, sl,
                                                  tw, talpha, tbeta, mixw, py);
  k_yred<<<2048, blk, 0, stream>>>(py, ybuf);

  k_gemm2<EPI_WO,64><<<dim3(16,16), blk, 0, stream>>>(ybuf, WoT, bo, x1, 2048, 1024, 1024, tgamma, x);

  k_ln<0><<<B_*T_, blk, 0, stream>>>(x1, ln2w, ln2b, xs);

  k_gemm2<EPI_BF16,128><<<dim3(24,16), blk, 0, stream>>>(xs, WkgT, bkg, kkb, 2048, 3072, 1024, nullptr, nullptr);
  k_gemm2<EPI_BF16,128><<<dim3(24,16), blk, 0, stream>>>(xs, WvgT, bvg, vvb, 2048, 3072, 1024, nullptr, nullptr);
  k_geglu<<<(2048*3072/8)/256, blk, 0, stream>>>(kkb, vvb, gb);
  k_gemm2<EPI_FFN2,64><<<dim3(16,16), blk, 0, stream>>>(gb, WwgT, bwg, d_out, 2048, 1024, 3072, x1, nullptr);
}

// Round 6
// 299.381 us; speedup vs baseline: 1.7607x; 1.1492x over previous
//
#include <hip/hip_runtime.h>
#include <cstdint>
#include <cstddef>
#include <cstdio>

// ---------------- constants ----------------
#define B_   2
#define T_   1024
#define C_   1024
#define H_   16
#define HS_  64
#define FFN_ 3072

typedef __bf16   bf16x8 __attribute__((ext_vector_type(8)));
typedef float    f32x4  __attribute__((ext_vector_type(4)));
typedef float    f32x16 __attribute__((ext_vector_type(16)));
typedef uint16_t u16x8  __attribute__((ext_vector_type(8)));

__device__ __forceinline__ uint16_t f2bf(float f){
  uint32_t u = __float_as_uint(f);
  u += 0x7FFFu + ((u >> 16) & 1u);          // RNE
  return (uint16_t)(u >> 16);
}
__device__ __forceinline__ float bf2f(uint16_t h){
  return __uint_as_float(((uint32_t)h) << 16);
}
__device__ __forceinline__ bf16x8 ldb8(const uint16_t* p){
  return __builtin_bit_cast(bf16x8, *reinterpret_cast<const u16x8*>(p));
}
__device__ __forceinline__ f32x4 mfma16(bf16x8 a, bf16x8 b, f32x4 c){
  return __builtin_amdgcn_mfma_f32_16x16x32_bf16(a, b, c, 0, 0, 0);
}

// async global->LDS, 16B per lane
typedef __attribute__((address_space(1))) const uint32_t* gas_t;
typedef __attribute__((address_space(3))) uint32_t* las_t;
__device__ __forceinline__ void gl_lds16(const uint16_t* g, uint16_t* l){
  __builtin_amdgcn_global_load_lds((gas_t)g, (las_t)l, 16, 0, 0);
}

// ---------------- transpose f32 [R][C] -> bf16 [C][R] ----------------
__global__ __launch_bounds__(256) void k_transpose(const float* __restrict__ in,
                                                   uint16_t* __restrict__ out,
                                                   int R, int Cc){
  __shared__ float tile[32][33];
  int c0 = blockIdx.x*32, r0 = blockIdx.y*32;
  int tx = threadIdx.x, ty = threadIdx.y;   // (32,8)
  #pragma unroll
  for (int i=0;i<4;i++) tile[ty+i*8][tx] = in[(size_t)(r0+ty+i*8)*Cc + c0+tx];
  __syncthreads();
  #pragma unroll
  for (int i=0;i<4;i++) out[(size_t)(c0+ty+i*8)*R + r0+tx] = f2bf(tile[tx][ty+i*8]);
}

// ---------------- concat biases: [bq|bk|bv] (3072) then [bkg|bvg] (6144) ----------------
__global__ void k_bcat(const float* __restrict__ bq, const float* __restrict__ bk,
                       const float* __restrict__ bv, const float* __restrict__ bkg,
                       const float* __restrict__ bvg, float* __restrict__ out){
  int i = blockIdx.x*256 + threadIdx.x;   // 9216
  float v;
  if      (i < 1024) v = bq[i];
  else if (i < 2048) v = bk[i-1024];
  else if (i < 3072) v = bv[i-2048];
  else if (i < 6144) v = bkg[i-3072];
  else               v = bvg[i-6144];
  out[i] = v;
}

// ---------------- LayerNorm (+optional time-shift-half scatter) ----------------
template<int SHIFT>
__global__ __launch_bounds__(256) void k_ln(const float* __restrict__ in,
                                            const float* __restrict__ w,
                                            const float* __restrict__ bia,
                                            uint16_t* __restrict__ out){
  int row = blockIdx.x;                 // b*T + t
  int t = row & (T_-1);
  const float* xr = in + (size_t)row*C_;
  float4 v = reinterpret_cast<const float4*>(xr)[threadIdx.x];
  float s  = v.x+v.y+v.z+v.w;
  float s2 = v.x*v.x+v.y*v.y+v.z*v.z+v.w*v.w;
  #pragma unroll
  for (int o=1;o<64;o<<=1){ s += __shfl_xor(s,o); s2 += __shfl_xor(s2,o); }
  __shared__ float red[8];
  int lane = threadIdx.x & 63, wid = threadIdx.x >> 6;
  if (lane == 0){ red[wid] = s; red[4+wid] = s2; }
  __syncthreads();
  s  = red[0]+red[1]+red[2]+red[3];
  s2 = red[4]+red[5]+red[6]+red[7];
  float mean = s * (1.f/1024.f);
  float var  = s2 * (1.f/1024.f) - mean*mean;
  float rs   = rsqrtf(var + 1e-5f);
  float vals[4] = {v.x, v.y, v.z, v.w};
  #pragma unroll
  for (int j=0;j<4;j++){
    int cc = threadIdx.x*4 + j;
    float o_ = (vals[j]-mean)*rs*w[cc] + bia[cc];
    uint16_t ob = f2bf(o_);
    if (SHIFT){
      if (cc < 512){
        if (t < T_-1) out[(size_t)(row+1)*C_ + cc] = ob;
        if (t == 0)   out[(size_t)row*C_ + cc] = 0;
      } else {
        out[(size_t)row*C_ + cc] = ob;
      }
    } else {
      out[(size_t)row*C_ + cc] = ob;
    }
  }
}

// ---------------- MFMA GEMM: C = A[M][K] * Bt[N][K]^T (+bias) ----------------
// tile 128 x BN, BK=32, 4 waves (2x2), global_load_lds staging (m97 structure)
enum { EPI_QKV=0, EPI_WO=2, EPI_BF16=3, EPI_FFN2=4 };

template<int EPI, int BN>
__global__ __launch_bounds__(256) void k_gemm2(
    const uint16_t* __restrict__ A, const uint16_t* __restrict__ Bt,
    const float* __restrict__ bias, void* __restrict__ outp,
    int M, int N, int K,
    const float* __restrict__ aux0, const float* __restrict__ aux1)
{
  __shared__ uint16_t As[128*32];
  __shared__ uint16_t Bs[BN*32];
  const int m0 = blockIdx.y*128, n0 = blockIdx.x*BN;
  const int tid = threadIdx.x;
  const int lane = tid & 63, wid = tid >> 6;
  const int wy = wid >> 1, wx = wid & 1;
  const int l16 = lane & 15, lr = lane >> 4;
  const int WN = BN/2;            // wave cols
  const int NW = BN/32;           // b-frags per wave
  const f32x4 z = {0.f,0.f,0.f,0.f};
  f32x4 acc[4][NW];
  #pragma unroll
  for (int m=0;m<4;m++)
    #pragma unroll
    for (int n=0;n<NW;n++) acc[m][n] = z;
  const int srow = tid >> 2, scol = (tid & 3)*8;
  for (int k0 = 0; k0 < K; k0 += 32){
    gl_lds16(A + (size_t)(m0 + srow)*K      + k0 + scol, As + tid*8);
    gl_lds16(A + (size_t)(m0 + 64 + srow)*K + k0 + scol, As + 2048 + tid*8);
    gl_lds16(Bt + (size_t)(n0 + srow)*K     + k0 + scol, Bs + tid*8);
    if constexpr (BN == 128)
      gl_lds16(Bt + (size_t)(n0 + 64 + srow)*K + k0 + scol, Bs + 2048 + tid*8);
    __syncthreads();
    bf16x8 af[4], bfr[NW];
    #pragma unroll
    for (int m=0;m<4;m++) af[m] = ldb8(As + (wy*64 + m*16 + l16)*32 + lr*8);
    #pragma unroll
    for (int n=0;n<NW;n++) bfr[n] = ldb8(Bs + (wx*WN + n*16 + l16)*32 + lr*8);
    #pragma unroll
    for (int m=0;m<4;m++)
      #pragma unroll
      for (int n=0;n<NW;n++) acc[m][n] = mfma16(af[m], bfr[n], acc[m][n]);
    __syncthreads();
  }
  if constexpr (EPI == EPI_QKV){
    // BN=64: one (kind,head) per block; wx==0 holds rotary pairs (d,d+16) as (n=0,n=1)
    const float linvf = exp2f(-(float)l16 * 0.83048202f);  // 10000^(-l16/16)
    #pragma unroll
    for (int m=0;m<4;m++){
      #pragma unroll
      for (int r=0;r<4;r++){
        int row = m0 + wy*64 + m*16 + lr*4 + r;
        int bb = row >> 10, t = row & 1023;
        int col0 = n0 + wx*32 + l16;
        float v0 = acc[m][0][r] + bias[col0];
        float v1 = acc[m][1][r] + bias[col0+16];
        int kind = col0 >> 10, hcol = col0 & 1023;
        int h = hcol >> 6, d0 = hcol & 63;
        if (kind < 2 && wx == 0){
          float sn, cs;
          __sincosf((float)t * linvf, &sn, &cs);
          float r0 = v0*cs - v1*sn;
          float r1 = v1*cs + v0*sn;
          v0 = r0; v1 = r1;
        }
        uint16_t* dst = (uint16_t*)outp + (size_t)kind*2097152;
        if (kind < 2){
          size_t basei = (((size_t)bb*16 + h)*1024 + t)*64;
          dst[basei + d0]      = f2bf(v0);
          dst[basei + d0 + 16] = f2bf(v1);
        } else {  // V transposed [b,h,d,t]
          size_t basei = ((size_t)bb*16 + h)*65536;
          dst[basei + (size_t)d0*1024 + t]      = f2bf(v0);
          dst[basei + (size_t)(d0+16)*1024 + t] = f2bf(v1);
        }
      }
    }
  } else {
    #pragma unroll
    for (int m=0;m<4;m++){
      #pragma unroll
      for (int n=0;n<NW;n++){
        int col = n0 + wx*WN + n*16 + l16;
        float bc_ = bias ? bias[col] : 0.f;
        #pragma unroll
        for (int r=0;r<4;r++){
          int row = m0 + wy*64 + m*16 + lr*4 + r;
          float v = acc[m][n][r] + bc_;
          if constexpr (EPI == EPI_WO){
            int t = row & (T_-1);
            ((float*)outp)[(size_t)row*N + col] = aux1[(size_t)row*N + col] + v*aux0[t];
          } else if constexpr (EPI == EPI_BF16){
            ((uint16_t*)outp)[(size_t)row*N + col] = f2bf(v);
          } else { // EPI_FFN2
            ((float*)outp)[(size_t)row*N + col] = aux0[(size_t)row*N + col] + v;
          }
        }
      }
    }
  }
}

// ---------------- pass A: softmax stats via per-lane ONLINE accumulation ----------------
__global__ __launch_bounds__(256) void k_stats(const uint16_t* __restrict__ q,
                                               const uint16_t* __restrict__ kmat,
                                               float* __restrict__ sm, float* __restrict__ sl){
  int bh = blockIdx.x, qb = blockIdx.y;
  int lane = threadIdx.x & 63, wid = threadIdx.x >> 6;
  int l16 = lane & 15, lr = lane >> 4;
  int r0 = qb*64 + wid*16;
  const uint16_t* qh = q    + (size_t)bh*T_*HS_;
  const uint16_t* kh = kmat + (size_t)bh*T_*HS_;
  int kq = lr*8;
  bf16x8 a0 = ldb8(qh + (size_t)(r0 + l16)*HS_ + kq);
  bf16x8 a1 = ldb8(qh + (size_t)(r0 + l16)*HS_ + kq + 32);
  float m_[4], l_[4]; int rows[4];
  #pragma unroll
  for (int r=0;r<4;r++){ m_[r] = -1e30f; l_[r] = 0.f; rows[r] = r0 + lr*4 + r; }
  int ktmax = (r0 + 15) >> 4;
  for (int kt = 0; kt <= ktmax; kt++){
    bf16x8 b0 = ldb8(kh + (size_t)(kt*16 + l16)*HS_ + kq);
    bf16x8 b1 = ldb8(kh + (size_t)(kt*16 + l16)*HS_ + kq + 32);
    f32x4 s = {0.f,0.f,0.f,0.f};
    s = mfma16(a0, b0, s);
    s = mfma16(a1, b1, s);
    int kcol = kt*16 + l16;
    #pragma unroll
    for (int r=0;r<4;r++){
      float sv = (kcol <= rows[r]) ? s[r]*0.125f : -3.0e38f;
      float mn = fmaxf(m_[r], sv);
      l_[r] = l_[r]*__expf(m_[r] - mn) + __expf(sv - mn);
      m_[r] = mn;
    }
  }
  #pragma unroll
  for (int o=1;o<16;o<<=1){
    #pragma unroll
    for (int r=0;r<4;r++){
      float mo = __shfl_xor(m_[r], o);
      float lo = __shfl_xor(l_[r], o);
      float mn = fmaxf(m_[r], mo);
      l_[r] = l_[r]*__expf(m_[r] - mn) + lo*__expf(mo - mn);
      m_[r] = mn;
    }
  }
  if (l16 == 0){
    #pragma unroll
    for (int r=0;r<4;r++){
      sm[(size_t)bh*T_ + rows[r]] = m_[r];
      sl[(size_t)bh*T_ + rows[r]] = l_[r];
    }
  }
}

// ---------------- fused attention v3: 16-row q tiles, 2 barriers/tile ----------------
// grid (kc=8 x 128cols, qt=64 x 16rows, b=2); 512 thr = 8 waves, wave w: heads {2w,2w+1}.
// U32 [pair-col c=wid][p=512] with bank rotation; Cm [16 o][520]; partials bf16.
__global__ __launch_bounds__(512, 4) void k_attn(
    const uint16_t* __restrict__ q, const uint16_t* __restrict__ kmat,
    const uint16_t* __restrict__ vT,
    const float* __restrict__ sm, const float* __restrict__ sl,
    const float* __restrict__ tw, const float* __restrict__ alpha,
    const float* __restrict__ beta, const float* __restrict__ mixw,
    uint16_t* __restrict__ py)
{
  int kc = blockIdx.x, qt = blockIdx.y, b = blockIdx.z;
  if (8*kc > qt) return;
  const int q0 = qt*16, ck0 = kc*128;
  const int lc = min(127, q0 + 15 - ck0);
  const int nt = (lc >> 5) + 1;

  __shared__ uint32_t U32[8*512];      // 16 KB
  __shared__ uint16_t Cm[16*520];      // 16.6 KB
  __shared__ float   TWL[16*144];      // 9.2 KB

  const int tid = threadIdx.x;
  const int lane = tid & 63;
  const int wid = __builtin_amdgcn_readfirstlane(tid >> 6);
  const int l16 = lane & 15, lr = lane >> 4;
  const int l32 = lane & 31, g32 = lane >> 5;

  const int base = 1008 - q0 + ck0;
  for (int i = tid; i < 16*144; i += 512){
    int h = i / 144, t = i - h*144;
    int gi = base + t;
    TWL[i] = (gi <= 1023) ? tw[h*1024 + gi] : 0.f;
  }

  float SM[2][4], BSL[2][4];
  bf16x8 qa[2][2];
  #pragma unroll
  for (int h2=0; h2<2; ++h2){
    int h = 2*wid + h2, bh = b*16 + h;
    #pragma unroll
    for (int r=0;r<4;r++){
      int qq = q0 + lr*4 + r;
      SM[h2][r]  = sm[(size_t)bh*1024 + qq];
      BSL[h2][r] = beta[(size_t)h*1024 + qq] / sl[(size_t)bh*1024 + qq];
    }
    #pragma unroll
    for (int kk=0;kk<2;kk++)
      qa[h2][kk] = ldb8(q + ((size_t)bh*1024 + q0 + l16)*64 + kk*32 + lr*8);
  }
  bf16x8 mwf;
  {
    u16x8 t8;
    #pragma unroll
    for (int j=0;j<8;j++){
      float v = (l32 < 16) ? mixw[l32*16 + g32*8 + j] : 0.f;
      t8[j] = f2bf(v);
    }
    mwf = __builtin_bit_cast(bf16x8, t8);
  }

  const f32x4 z = {0.f,0.f,0.f,0.f};
  f32x4 acc[2][4];
  #pragma unroll
  for (int oo=0;oo<2;oo++) for (int n=0;n<4;n++) acc[oo][n] = z;

  __syncthreads();   // TWL ready

  for (int t = 0; t < nt; ++t){
    const int k0 = ck0 + t*32;
    // ---- QK^T (2 heads) ----
    f32x4 s[2][2];
    s[0][0]=z; s[0][1]=z; s[1][0]=z; s[1][1]=z;
    #pragma unroll
    for (int h2=0;h2<2;h2++){
      const uint16_t* kh = kmat + ((size_t)(b*16 + 2*wid + h2)*1024 + k0)*64;
      #pragma unroll
      for (int kk=0;kk<2;kk++){
        bf16x8 kb0 = ldb8(kh + (size_t)(l16)*64      + kk*32 + lr*8);
        bf16x8 kb1 = ldb8(kh + (size_t)(16 + l16)*64 + kk*32 + lr*8);
        s[h2][0] = mfma16(qa[h2][kk], kb0, s[h2][0]);
        s[h2][1] = mfma16(qa[h2][kk], kb1, s[h2][1]);
      }
    }
    // ---- u = exp(s/8 - m)*beta/l*alpha*tw -> U32 (bank-rotated, 2-way max) ----
    #pragma unroll
    for (int n=0;n<2;n++){
      int kloc = n*16 + l16;
      int kg = k0 + kloc;
      float al0 = alpha[(2*wid+0)*1024 + kg];
      float al1 = alpha[(2*wid+1)*1024 + kg];
      #pragma unroll
      for (int r=0;r<4;r++){
        int qloc = lr*4 + r;
        bool ok = (kg <= q0 + qloc);
        int twi = 15 - qloc + (kg - ck0);
        float u0 = 0.f, u1 = 0.f;
        if (ok){
          u0 = __expf(s[0][n][r]*0.125f - SM[0][r]) * BSL[0][r] * al0 * TWL[(2*wid+0)*144 + twi];
          u1 = __expf(s[1][n][r]*0.125f - SM[1][r]) * BSL[1][r] * al1 * TWL[(2*wid+1)*144 + twi];
        }
        uint32_t pk = (uint32_t)f2bf(u0) | ((uint32_t)f2bf(u1) << 16);
        U32[wid*512 + qloc*32 + ((kloc + 8*(qloc>>2)) & 31)] = pk;
      }
    }
    __syncthreads();   // B1: U complete
    // ---- head-mix via 32x32x16 MFMA: one q-row x 32 k x 16 heads per MFMA ----
    #pragma unroll
    for (int cc=0; cc<2; ++cc){
      int qrow = wid*2 + cc;
      int pbase = qrow*32;
      int swz = (l32 + 8*(qrow>>2)) & 31;
      u16x8 a8;
      uint32_t* a32 = reinterpret_cast<uint32_t*>(&a8);
      #pragma unroll
      for (int j=0;j<4;j++)
        a32[j] = U32[(4*g32 + j)*512 + pbase + swz];
      bf16x8 a = __builtin_bit_cast(bf16x8, a8);
      f32x16 zz{};
      f32x16 dd = __builtin_amdgcn_mfma_f32_32x32x16_bf16(a, mwf, zz, 0, 0, 0);
      if (l32 < 16){
        int o = l32;
        #pragma unroll
        for (int rg=0; rg<4; ++rg){
          int p0 = pbase + rg*8 + g32*4;
          uint32_t w0 = (uint32_t)f2bf(dd[4*rg+0]) | ((uint32_t)f2bf(dd[4*rg+1]) << 16);
          uint32_t w1 = (uint32_t)f2bf(dd[4*rg+2]) | ((uint32_t)f2bf(dd[4*rg+3]) << 16);
          uint2 pk2; pk2.x = w0; pk2.y = w1;
          *reinterpret_cast<uint2*>(Cm + (size_t)o*520 + p0) = pk2;
        }
      }
    }
    __syncthreads();   // B2: Cm complete (also fences U reads vs next tile's writes)
    // ---- PV (2 output heads); no barrier after: next mix waits at B1 ----
    #pragma unroll
    for (int oo=0;oo<2;oo++){
      int o = 2*wid + oo;
      bf16x8 cf = ldb8(Cm + (size_t)o*520 + l16*32 + lr*8);
      const uint16_t* vh = vT + (size_t)(b*16 + o)*64*1024;
      #pragma unroll
      for (int n=0;n<4;n++){
        bf16x8 vf = ldb8(vh + (size_t)(n*16 + l16)*1024 + k0 + lr*8);
        acc[oo][n] = mfma16(cf, vf, acc[oo][n]);
      }
    }
  }

  uint16_t* po = py + (((size_t)(b*64 + qt))*8 + kc)*16384;
  #pragma unroll
  for (int oo=0;oo<2;oo++){
    int o = 2*wid + oo;
    #pragma unroll
    for (int n=0;n<4;n++)
      #pragma unroll
      for (int r=0;r<4;r++){
        int qloc = lr*4 + r;
        po[o*1024 + qloc*64 + n*16 + l16] = f2bf(acc[oo][n][r]);
      }
  }
}

// ---------------- reduce bf16 partials -> ybuf bf16 [B,T,C] ----------------
__global__ void k_yred(const uint16_t* __restrict__ py, uint16_t* __restrict__ y){
  int idx = blockIdx.x*256 + threadIdx.x;   // 262144, one bf16x8 each
  int d8 = idx & 7, qq = (idx>>3)&15, o = (idx>>7)&15, qt = (idx>>11)&63, b = idx>>17;
  int nch = (qt>>3) + 1;
  const uint16_t* p0 = py + (((size_t)(b*64+qt))*8)*16384 + o*1024 + qq*64 + d8*8;
  float s[8] = {0,0,0,0,0,0,0,0};
  for (int kc=0; kc<nch; kc++){
    u16x8 v = *reinterpret_cast<const u16x8*>(p0 + (size_t)kc*16384);
    #pragma unroll
    for (int e=0;e<8;e++) s[e] += bf2f(v[e]);
  }
  int t = qt*16 + qq;
  u16x8 w;
  #pragma unroll
  for (int e=0;e<8;e++) w[e] = f2bf(s[e]);
  *reinterpret_cast<u16x8*>(y + ((size_t)(b*1024 + t))*1024 + o*64 + d8*8) = w;
}

// ---------------- GEGLU: g[row][j] = gelu(ffu[row][j]) * ffu[row][j+3072] ----------------
__global__ void k_geglu(const uint16_t* __restrict__ ffu, uint16_t* __restrict__ g){
  int i = blockIdx.x*256 + threadIdx.x;      // 2048*384
  int row = i / 384, j8 = i - row*384;
  const uint16_t* pa = ffu + (size_t)row*6144 + j8*8;
  u16x8 a = *reinterpret_cast<const u16x8*>(pa);
  u16x8 b = *reinterpret_cast<const u16x8*>(pa + 3072);
  u16x8 o;
  #pragma unroll
  for (int e=0;e<8;e++){
    float xv = bf2f(a[e]);
    float gl = 0.5f*xv*(1.f + erff(xv*0.70710678118f));
    o[e] = f2bf(gl * bf2f(b[e]));
  }
  *reinterpret_cast<u16x8*>(g + (size_t)row*3072 + j8*8) = o;
}

// ---------------- host ----------------
extern "C" void kernel_launch(void* const* d_in, const int* in_sizes, int n_in,
                              void* d_out, int out_size, void* d_ws, size_t ws_size,
                              hipStream_t stream)
{
  const float* x      = (const float*)d_in[0];
  const float* ln1w   = (const float*)d_in[1];
  const float* ln1b   = (const float*)d_in[2];
  const float* ln2w   = (const float*)d_in[3];
  const float* ln2b   = (const float*)d_in[4];
  const float* Wq     = (const float*)d_in[5];
  const float* bq     = (const float*)d_in[6];
  const float* Wk     = (const float*)d_in[7];
  const float* bk     = (const float*)d_in[8];
  const float* Wv     = (const float*)d_in[9];
  const float* bv     = (const float*)d_in[10];
  const float* Wo     = (const float*)d_in[11];
  const float* bo     = (const float*)d_in[12];
  const float* tw     = (const float*)d_in[13];
  const float* talpha = (const float*)d_in[14];
  const float* tbeta  = (const float*)d_in[15];
  const float* tgamma = (const float*)d_in[16];
  const float* mixw   = (const float*)d_in[17];
  const float* Wkg    = (const float*)d_in[18];
  const float* bkg    = (const float*)d_in[19];
  const float* Wvg    = (const float*)d_in[20];
  const float* bvg    = (const float*)d_in[21];
  const float* Wwg    = (const float*)d_in[22];
  const float* bwg    = (const float*)d_in[23];

  char* ws = (char*)d_ws;
  size_t off = 0;
  auto alloc = [&](size_t bytes)->char*{
    char* p = ws + off; off += (bytes + 255) & ~(size_t)255; return p;
  };
  uint16_t* WqT  = (uint16_t*)alloc((size_t)C_*C_*2);     // contiguous q|k|v
  uint16_t* WkT  = (uint16_t*)alloc((size_t)C_*C_*2);
  uint16_t* WvT  = (uint16_t*)alloc((size_t)C_*C_*2);
  uint16_t* WoT  = (uint16_t*)alloc((size_t)C_*C_*2);
  uint16_t* WkgT = (uint16_t*)alloc((size_t)FFN_*C_*2);   // contiguous kg|vg
  uint16_t* WvgT = (uint16_t*)alloc((size_t)FFN_*C_*2);
  uint16_t* WwgT = (uint16_t*)alloc((size_t)C_*FFN_*2);
  uint16_t* xs   = (uint16_t*)alloc((size_t)B_*T_*C_*2);
  uint16_t* qbuf = (uint16_t*)alloc((size_t)B_*T_*C_*2);  // contiguous q|k|vT
  uint16_t* kbuf = (uint16_t*)alloc((size_t)B_*T_*C_*2);
  uint16_t* vT   = (uint16_t*)alloc((size_t)B_*T_*C_*2);
  float*    sm   = (float*)alloc((size_t)B_*H_*T_*4);
  float*    sl   = (float*)alloc((size_t)B_*H_*T_*4);
  uint16_t* ybuf = (uint16_t*)alloc((size_t)B_*T_*C_*2);
  float*    x1   = (float*)alloc((size_t)B_*T_*C_*4);
  float*    bcat = (float*)alloc((size_t)9216*4);
  char*     region = alloc((size_t)64*1024*1024);
  uint16_t* py  = (uint16_t*)region;                       // 32 MB bf16 partials
  uint16_t* ffu = (uint16_t*)region;                       // 25.2 MB (after attn done)
  uint16_t* gb  = (uint16_t*)(region + (size_t)2048*6144*2);

  if (off > ws_size){
    fprintf(stderr, "kernel_launch: ws too small (%zu needed, %zu given)\n", off, ws_size);
    return;
  }

  dim3 blk(256);
  dim3 tblk(32,8);
  k_transpose<<<dim3(32,32), tblk, 0, stream>>>(Wq,  WqT,  C_,  C_);
  k_transpose<<<dim3(32,32), tblk, 0, stream>>>(Wk,  WkT,  C_,  C_);
  k_transpose<<<dim3(32,32), tblk, 0, stream>>>(Wv,  WvT,  C_,  C_);
  k_transpose<<<dim3(32,32), tblk, 0, stream>>>(Wo,  WoT,  C_,  C_);
  k_transpose<<<dim3(96,32), tblk, 0, stream>>>(Wkg, WkgT, C_,  FFN_);
  k_transpose<<<dim3(96,32), tblk, 0, stream>>>(Wvg, WvgT, C_,  FFN_);
  k_transpose<<<dim3(32,96), tblk, 0, stream>>>(Wwg, WwgT, FFN_, C_);
  k_bcat<<<36, blk, 0, stream>>>(bq, bk, bv, bkg, bvg, bcat);

  k_ln<1><<<B_*T_, blk, 0, stream>>>(x, ln1w, ln1b, xs);

  // fused QKV (N=3072) with RoPE + scatter epilogue
  k_gemm2<EPI_QKV,64><<<dim3(48,16), blk, 0, stream>>>(xs, WqT, bcat, qbuf, 2048, 3072, 1024, nullptr, nullptr);

  k_stats<<<dim3(B_*H_, T_/64), blk, 0, stream>>>(qbuf, kbuf, sm, sl);
  k_attn<<<dim3(8,64,B_), dim3(512), 0, stream>>>(qbuf, kbuf, vT, sm, sl,
                                                  tw, talpha, tbeta, mixw, py);
  k_yred<<<1024, blk, 0, stream>>>(py, ybuf);

  k_gemm2<EPI_WO,64><<<dim3(16,16), blk, 0, stream>>>(ybuf, WoT, bo, x1, 2048, 1024, 1024, tgamma, x);

  k_ln<0><<<B_*T_, blk, 0, stream>>>(x1, ln2w, ln2b, xs);

  // fused FFN-up (N=6144)
  k_gemm2<EPI_BF16,128><<<dim3(48,16), blk, 0, stream>>>(xs, WkgT, bcat+3072, ffu, 2048, 6144, 1024, nullptr, nullptr);
  k_geglu<<<3072, blk, 0, stream>>>(ffu, gb);
  k_gemm2<EPI_FFN2,64><<<dim3(16,16), blk, 0, stream>>>(gb, WwgT, bwg, d_out, 2048, 1024, 3072, x1, nullptr);
}

// Round 7
// 293.700 us; speedup vs baseline: 1.7948x; 1.0193x over previous
//
#include <hip/hip_runtime.h>
#include <cstdint>
#include <cstddef>
#include <cstdio>

// ---------------- constants ----------------
#define B_   2
#define T_   1024
#define C_   1024
#define H_   16
#define HS_  64
#define FFN_ 3072

typedef __bf16   bf16x8 __attribute__((ext_vector_type(8)));
typedef float    f32x4  __attribute__((ext_vector_type(4)));
typedef float    f32x16 __attribute__((ext_vector_type(16)));
typedef uint16_t u16x8  __attribute__((ext_vector_type(8)));

__device__ __forceinline__ uint16_t f2bf(float f){
  uint32_t u = __float_as_uint(f);
  u += 0x7FFFu + ((u >> 16) & 1u);          // RNE
  return (uint16_t)(u >> 16);
}
__device__ __forceinline__ float bf2f(uint16_t h){
  return __uint_as_float(((uint32_t)h) << 16);
}
__device__ __forceinline__ bf16x8 ldb8(const uint16_t* p){
  return __builtin_bit_cast(bf16x8, *reinterpret_cast<const u16x8*>(p));
}
__device__ __forceinline__ f32x4 mfma16(bf16x8 a, bf16x8 b, f32x4 c){
  return __builtin_amdgcn_mfma_f32_16x16x32_bf16(a, b, c, 0, 0, 0);
}

// async global->LDS, 16B per lane
typedef __attribute__((address_space(1))) const uint32_t* gas_t;
typedef __attribute__((address_space(3))) uint32_t* las_t;
__device__ __forceinline__ void gl_lds16(const uint16_t* g, uint16_t* l){
  __builtin_amdgcn_global_load_lds((gas_t)g, (las_t)l, 16, 0, 0);
}

// ---------------- transpose f32 [R][C] -> bf16 [C][R] ----------------
__global__ __launch_bounds__(256) void k_transpose(const float* __restrict__ in,
                                                   uint16_t* __restrict__ out,
                                                   int R, int Cc){
  __shared__ float tile[32][33];
  int c0 = blockIdx.x*32, r0 = blockIdx.y*32;
  int tx = threadIdx.x, ty = threadIdx.y;   // (32,8)
  #pragma unroll
  for (int i=0;i<4;i++) tile[ty+i*8][tx] = in[(size_t)(r0+ty+i*8)*Cc + c0+tx];
  __syncthreads();
  #pragma unroll
  for (int i=0;i<4;i++) out[(size_t)(c0+ty+i*8)*R + r0+tx] = f2bf(tile[tx][ty+i*8]);
}

// ---------------- concat biases: [bq|bk|bv] (3072) then [bkg|bvg] (6144) ----------------
__global__ void k_bcat(const float* __restrict__ bq, const float* __restrict__ bk,
                       const float* __restrict__ bv, const float* __restrict__ bkg,
                       const float* __restrict__ bvg, float* __restrict__ out){
  int i = blockIdx.x*256 + threadIdx.x;   // 9216
  float v;
  if      (i < 1024) v = bq[i];
  else if (i < 2048) v = bk[i-1024];
  else if (i < 3072) v = bv[i-2048];
  else if (i < 6144) v = bkg[i-3072];
  else               v = bvg[i-6144];
  out[i] = v;
}

// ---------------- LayerNorm (+optional time-shift-half scatter) ----------------
template<int SHIFT>
__global__ __launch_bounds__(256) void k_ln(const float* __restrict__ in,
                                            const float* __restrict__ w,
                                            const float* __restrict__ bia,
                                            uint16_t* __restrict__ out){
  int row = blockIdx.x;                 // b*T + t
  int t = row & (T_-1);
  const float* xr = in + (size_t)row*C_;
  float4 v = reinterpret_cast<const float4*>(xr)[threadIdx.x];
  float s  = v.x+v.y+v.z+v.w;
  float s2 = v.x*v.x+v.y*v.y+v.z*v.z+v.w*v.w;
  #pragma unroll
  for (int o=1;o<64;o<<=1){ s += __shfl_xor(s,o); s2 += __shfl_xor(s2,o); }
  __shared__ float red[8];
  int lane = threadIdx.x & 63, wid = threadIdx.x >> 6;
  if (lane == 0){ red[wid] = s; red[4+wid] = s2; }
  __syncthreads();
  s  = red[0]+red[1]+red[2]+red[3];
  s2 = red[4]+red[5]+red[6]+red[7];
  float mean = s * (1.f/1024.f);
  float var  = s2 * (1.f/1024.f) - mean*mean;
  float rs   = rsqrtf(var + 1e-5f);
  float vals[4] = {v.x, v.y, v.z, v.w};
  #pragma unroll
  for (int j=0;j<4;j++){
    int cc = threadIdx.x*4 + j;
    float o_ = (vals[j]-mean)*rs*w[cc] + bia[cc];
    uint16_t ob = f2bf(o_);
    if (SHIFT){
      if (cc < 512){
        if (t < T_-1) out[(size_t)(row+1)*C_ + cc] = ob;
        if (t == 0)   out[(size_t)row*C_ + cc] = 0;
      } else {
        out[(size_t)row*C_ + cc] = ob;
      }
    } else {
      out[(size_t)row*C_ + cc] = ob;
    }
  }
}

// ---------------- MFMA GEMM: C = A[M][K] * Bt[N][K]^T (+bias) ----------------
// tile 128 x BN, BK=32, 4 waves (2x2), global_load_lds staging (m97 structure)
enum { EPI_QKV=0, EPI_WO=2, EPI_BF16=3, EPI_FFN2=4 };

template<int EPI, int BN>
__global__ __launch_bounds__(256) void k_gemm2(
    const uint16_t* __restrict__ A, const uint16_t* __restrict__ Bt,
    const float* __restrict__ bias, void* __restrict__ outp,
    int M, int N, int K,
    const float* __restrict__ aux0, const float* __restrict__ aux1)
{
  __shared__ uint16_t As[128*32];
  __shared__ uint16_t Bs[BN*32];
  const int m0 = blockIdx.y*128, n0 = blockIdx.x*BN;
  const int tid = threadIdx.x;
  const int lane = tid & 63, wid = tid >> 6;
  const int wy = wid >> 1, wx = wid & 1;
  const int l16 = lane & 15, lr = lane >> 4;
  const int WN = BN/2;            // wave cols
  const int NW = BN/32;           // b-frags per wave
  const f32x4 z = {0.f,0.f,0.f,0.f};
  f32x4 acc[4][NW];
  #pragma unroll
  for (int m=0;m<4;m++)
    #pragma unroll
    for (int n=0;n<NW;n++) acc[m][n] = z;
  const int srow = tid >> 2, scol = (tid & 3)*8;
  for (int k0 = 0; k0 < K; k0 += 32){
    gl_lds16(A + (size_t)(m0 + srow)*K      + k0 + scol, As + tid*8);
    gl_lds16(A + (size_t)(m0 + 64 + srow)*K + k0 + scol, As + 2048 + tid*8);
    gl_lds16(Bt + (size_t)(n0 + srow)*K     + k0 + scol, Bs + tid*8);
    if constexpr (BN == 128)
      gl_lds16(Bt + (size_t)(n0 + 64 + srow)*K + k0 + scol, Bs + 2048 + tid*8);
    __syncthreads();
    bf16x8 af[4], bfr[NW];
    #pragma unroll
    for (int m=0;m<4;m++) af[m] = ldb8(As + (wy*64 + m*16 + l16)*32 + lr*8);
    #pragma unroll
    for (int n=0;n<NW;n++) bfr[n] = ldb8(Bs + (wx*WN + n*16 + l16)*32 + lr*8);
    #pragma unroll
    for (int m=0;m<4;m++)
      #pragma unroll
      for (int n=0;n<NW;n++) acc[m][n] = mfma16(af[m], bfr[n], acc[m][n]);
    __syncthreads();
  }
  if constexpr (EPI == EPI_QKV){
    // BN=64: one (kind,head) per block; wx==0 holds rotary pairs (d,d+16) as (n=0,n=1)
    const float linvf = exp2f(-(float)l16 * 0.83048202f);  // 10000^(-l16/16)
    #pragma unroll
    for (int m=0;m<4;m++){
      #pragma unroll
      for (int r=0;r<4;r++){
        int row = m0 + wy*64 + m*16 + lr*4 + r;
        int bb = row >> 10, t = row & 1023;
        int col0 = n0 + wx*32 + l16;
        float v0 = acc[m][0][r] + bias[col0];
        float v1 = acc[m][1][r] + bias[col0+16];
        int kind = col0 >> 10, hcol = col0 & 1023;
        int h = hcol >> 6, d0 = hcol & 63;
        if (kind < 2 && wx == 0){
          float sn, cs;
          __sincosf((float)t * linvf, &sn, &cs);
          float r0 = v0*cs - v1*sn;
          float r1 = v1*cs + v0*sn;
          v0 = r0; v1 = r1;
        }
        uint16_t* dst = (uint16_t*)outp + (size_t)kind*2097152;
        if (kind < 2){
          size_t basei = (((size_t)bb*16 + h)*1024 + t)*64;
          dst[basei + d0]      = f2bf(v0);
          dst[basei + d0 + 16] = f2bf(v1);
        } else {  // V transposed [b,h,d,t]
          size_t basei = ((size_t)bb*16 + h)*65536;
          dst[basei + (size_t)d0*1024 + t]      = f2bf(v0);
          dst[basei + (size_t)(d0+16)*1024 + t] = f2bf(v1);
        }
      }
    }
  } else {
    #pragma unroll
    for (int m=0;m<4;m++){
      #pragma unroll
      for (int n=0;n<NW;n++){
        int col = n0 + wx*WN + n*16 + l16;
        float bc_ = bias ? bias[col] : 0.f;
        #pragma unroll
        for (int r=0;r<4;r++){
          int row = m0 + wy*64 + m*16 + lr*4 + r;
          float v = acc[m][n][r] + bc_;
          if constexpr (EPI == EPI_WO){
            int t = row & (T_-1);
            ((float*)outp)[(size_t)row*N + col] = aux1[(size_t)row*N + col] + v*aux0[t];
          } else if constexpr (EPI == EPI_BF16){
            ((uint16_t*)outp)[(size_t)row*N + col] = f2bf(v);
          } else { // EPI_FFN2
            ((float*)outp)[(size_t)row*N + col] = aux0[(size_t)row*N + col] + v;
          }
        }
      }
    }
  }
}

// ---------------- pass A: softmax stats via per-lane ONLINE accumulation ----------------
__global__ __launch_bounds__(256) void k_stats(const uint16_t* __restrict__ q,
                                               const uint16_t* __restrict__ kmat,
                                               float* __restrict__ sm, float* __restrict__ sl){
  int bh = blockIdx.x, qb = blockIdx.y;
  int lane = threadIdx.x & 63, wid = threadIdx.x >> 6;
  int l16 = lane & 15, lr = lane >> 4;
  int r0 = qb*64 + wid*16;
  const uint16_t* qh = q    + (size_t)bh*T_*HS_;
  const uint16_t* kh = kmat + (size_t)bh*T_*HS_;
  int kq = lr*8;
  bf16x8 a0 = ldb8(qh + (size_t)(r0 + l16)*HS_ + kq);
  bf16x8 a1 = ldb8(qh + (size_t)(r0 + l16)*HS_ + kq + 32);
  float m_[4], l_[4]; int rows[4];
  #pragma unroll
  for (int r=0;r<4;r++){ m_[r] = -1e30f; l_[r] = 0.f; rows[r] = r0 + lr*4 + r; }
  int ktmax = (r0 + 15) >> 4;
  for (int kt = 0; kt <= ktmax; kt++){
    bf16x8 b0 = ldb8(kh + (size_t)(kt*16 + l16)*HS_ + kq);
    bf16x8 b1 = ldb8(kh + (size_t)(kt*16 + l16)*HS_ + kq + 32);
    f32x4 s = {0.f,0.f,0.f,0.f};
    s = mfma16(a0, b0, s);
    s = mfma16(a1, b1, s);
    int kcol = kt*16 + l16;
    #pragma unroll
    for (int r=0;r<4;r++){
      float sv = (kcol <= rows[r]) ? s[r]*0.125f : -3.0e38f;
      float mn = fmaxf(m_[r], sv);
      l_[r] = l_[r]*__expf(m_[r] - mn) + __expf(sv - mn);
      m_[r] = mn;
    }
  }
  #pragma unroll
  for (int o=1;o<16;o<<=1){
    #pragma unroll
    for (int r=0;r<4;r++){
      float mo = __shfl_xor(m_[r], o);
      float lo = __shfl_xor(l_[r], o);
      float mn = fmaxf(m_[r], mo);
      l_[r] = l_[r]*__expf(m_[r] - mn) + lo*__expf(mo - mn);
      m_[r] = mn;
    }
  }
  if (l16 == 0){
    #pragma unroll
    for (int r=0;r<4;r++){
      sm[(size_t)bh*T_ + rows[r]] = m_[r];
      sl[(size_t)bh*T_ + rows[r]] = l_[r];
    }
  }
}

// ---------------- fused attention v4: 16-row q tiles, bf16 TWL, qt-fast grid ----------------
// grid (qt=64 x 16rows, kc=8 x 128cols, b=2); 512 thr = 8 waves, wave w: heads {2w,2w+1}.
// U32 [pair-col c=wid][p=512] with bank rotation; Cm [16 o][520]; partials bf16.
__global__ __launch_bounds__(512, 4) void k_attn(
    const uint16_t* __restrict__ q, const uint16_t* __restrict__ kmat,
    const uint16_t* __restrict__ vT,
    const float* __restrict__ sm, const float* __restrict__ sl,
    const float* __restrict__ tw, const float* __restrict__ alpha,
    const float* __restrict__ beta, const float* __restrict__ mixw,
    uint16_t* __restrict__ py)
{
  int qt = blockIdx.x, kc = blockIdx.y, b = blockIdx.z;
  if (8*kc > qt) return;
  const int q0 = qt*16, ck0 = kc*128;
  const int lc = min(127, q0 + 15 - ck0);
  const int nt = (lc >> 5) + 1;

  __shared__ uint32_t U32[8*512];      // 16 KB
  __shared__ uint16_t Cm[16*520];      // 16.6 KB
  __shared__ uint16_t TWL[16*160];     // 5 KB (bf16)

  const int tid = threadIdx.x;
  const int lane = tid & 63;
  const int wid = __builtin_amdgcn_readfirstlane(tid >> 6);
  const int l16 = lane & 15, lr = lane >> 4;
  const int l32 = lane & 31, g32 = lane >> 5;

  const int base = 1008 - q0 + ck0;
  for (int i = tid; i < 16*144; i += 512){
    int h = i / 144, t = i - h*144;
    int gi = base + t;
    TWL[h*160 + t] = (gi <= 1023) ? f2bf(tw[h*1024 + gi]) : (uint16_t)0;
  }

  float SM[2][4], BSL[2][4];
  bf16x8 qa[2][2];
  #pragma unroll
  for (int h2=0; h2<2; ++h2){
    int h = 2*wid + h2, bh = b*16 + h;
    float4 s4 = *reinterpret_cast<const float4*>(sm   + (size_t)bh*1024 + q0 + lr*4);
    float4 l4 = *reinterpret_cast<const float4*>(sl   + (size_t)bh*1024 + q0 + lr*4);
    float4 b4 = *reinterpret_cast<const float4*>(beta + (size_t)h*1024  + q0 + lr*4);
    SM[h2][0]=s4.x; SM[h2][1]=s4.y; SM[h2][2]=s4.z; SM[h2][3]=s4.w;
    BSL[h2][0]=b4.x/l4.x; BSL[h2][1]=b4.y/l4.y; BSL[h2][2]=b4.z/l4.z; BSL[h2][3]=b4.w/l4.w;
    #pragma unroll
    for (int kk=0;kk<2;kk++)
      qa[h2][kk] = ldb8(q + ((size_t)bh*1024 + q0 + l16)*64 + kk*32 + lr*8);
  }
  bf16x8 mwf;
  {
    u16x8 t8;
    #pragma unroll
    for (int j=0;j<8;j++){
      float v = (l32 < 16) ? mixw[l32*16 + g32*8 + j] : 0.f;
      t8[j] = f2bf(v);
    }
    mwf = __builtin_bit_cast(bf16x8, t8);
  }

  const f32x4 z = {0.f,0.f,0.f,0.f};
  f32x4 acc[2][4];
  #pragma unroll
  for (int oo=0;oo<2;oo++) for (int n=0;n<4;n++) acc[oo][n] = z;

  __syncthreads();   // TWL ready

  for (int t = 0; t < nt; ++t){
    const int k0 = ck0 + t*32;
    // ---- QK^T (2 heads) ----
    f32x4 s[2][2];
    s[0][0]=z; s[0][1]=z; s[1][0]=z; s[1][1]=z;
    #pragma unroll
    for (int h2=0;h2<2;h2++){
      const uint16_t* kh = kmat + ((size_t)(b*16 + 2*wid + h2)*1024 + k0)*64;
      #pragma unroll
      for (int kk=0;kk<2;kk++){
        bf16x8 kb0 = ldb8(kh + (size_t)(l16)*64      + kk*32 + lr*8);
        bf16x8 kb1 = ldb8(kh + (size_t)(16 + l16)*64 + kk*32 + lr*8);
        s[h2][0] = mfma16(qa[h2][kk], kb0, s[h2][0]);
        s[h2][1] = mfma16(qa[h2][kk], kb1, s[h2][1]);
      }
    }
    // ---- u = exp(s/8 - m)*beta/l*alpha*tw -> U32 (bank-rotated, 2-way max) ----
    #pragma unroll
    for (int n=0;n<2;n++){
      int kloc = n*16 + l16;
      int kg = k0 + kloc;
      float al0 = alpha[(2*wid+0)*1024 + kg];
      float al1 = alpha[(2*wid+1)*1024 + kg];
      #pragma unroll
      for (int r=0;r<4;r++){
        int qloc = lr*4 + r;
        bool ok = (kg <= q0 + qloc);
        int twi = 15 - qloc + (kg - ck0);
        float u0 = 0.f, u1 = 0.f;
        if (ok){
          u0 = __expf(s[0][n][r]*0.125f - SM[0][r]) * BSL[0][r] * al0 * bf2f(TWL[(2*wid+0)*160 + twi]);
          u1 = __expf(s[1][n][r]*0.125f - SM[1][r]) * BSL[1][r] * al1 * bf2f(TWL[(2*wid+1)*160 + twi]);
        }
        uint32_t pk = (uint32_t)f2bf(u0) | ((uint32_t)f2bf(u1) << 16);
        U32[wid*512 + qloc*32 + ((kloc + 8*(qloc>>2)) & 31)] = pk;
      }
    }
    __syncthreads();   // B1: U complete
    // ---- head-mix via 32x32x16 MFMA: one q-row x 32 k x 16 heads per MFMA ----
    #pragma unroll
    for (int cc=0; cc<2; ++cc){
      int qrow = wid*2 + cc;
      int pbase = qrow*32;
      int swz = (l32 + 8*(qrow>>2)) & 31;
      u16x8 a8;
      uint32_t* a32 = reinterpret_cast<uint32_t*>(&a8);
      #pragma unroll
      for (int j=0;j<4;j++)
        a32[j] = U32[(4*g32 + j)*512 + pbase + swz];
      bf16x8 a = __builtin_bit_cast(bf16x8, a8);
      f32x16 zz{};
      f32x16 dd = __builtin_amdgcn_mfma_f32_32x32x16_bf16(a, mwf, zz, 0, 0, 0);
      if (l32 < 16){
        int o = l32;
        #pragma unroll
        for (int rg=0; rg<4; ++rg){
          int p0 = pbase + rg*8 + g32*4;
          uint32_t w0 = (uint32_t)f2bf(dd[4*rg+0]) | ((uint32_t)f2bf(dd[4*rg+1]) << 16);
          uint32_t w1 = (uint32_t)f2bf(dd[4*rg+2]) | ((uint32_t)f2bf(dd[4*rg+3]) << 16);
          uint2 pk2; pk2.x = w0; pk2.y = w1;
          *reinterpret_cast<uint2*>(Cm + (size_t)o*520 + p0) = pk2;
        }
      }
    }
    __syncthreads();   // B2: Cm complete (also fences U reads vs next tile's writes)
    // ---- PV (2 output heads); no barrier after: next mix waits at B1 ----
    #pragma unroll
    for (int oo=0;oo<2;oo++){
      int o = 2*wid + oo;
      bf16x8 cf = ldb8(Cm + (size_t)o*520 + l16*32 + lr*8);
      const uint16_t* vh = vT + (size_t)(b*16 + o)*64*1024;
      #pragma unroll
      for (int n=0;n<4;n++){
        bf16x8 vf = ldb8(vh + (size_t)(n*16 + l16)*1024 + k0 + lr*8);
        acc[oo][n] = mfma16(cf, vf, acc[oo][n]);
      }
    }
  }

  uint16_t* po = py + (((size_t)(b*64 + qt))*8 + kc)*16384;
  #pragma unroll
  for (int oo=0;oo<2;oo++){
    int o = 2*wid + oo;
    #pragma unroll
    for (int n=0;n<4;n++)
      #pragma unroll
      for (int r=0;r<4;r++){
        int qloc = lr*4 + r;
        po[o*1024 + qloc*64 + n*16 + l16] = f2bf(acc[oo][n][r]);
      }
  }
}

// ---------------- reduce bf16 partials -> ybuf bf16 [B,T,C] ----------------
__global__ void k_yred(const uint16_t* __restrict__ py, uint16_t* __restrict__ y){
  int idx = blockIdx.x*256 + threadIdx.x;   // 262144, one bf16x8 each
  int d8 = idx & 7, qq = (idx>>3)&15, o = (idx>>7)&15, qt = (idx>>11)&63, b = idx>>17;
  int nch = (qt>>3) + 1;
  const uint16_t* p0 = py + (((size_t)(b*64+qt))*8)*16384 + o*1024 + qq*64 + d8*8;
  float s[8] = {0,0,0,0,0,0,0,0};
  for (int kc=0; kc<nch; kc++){
    u16x8 v = *reinterpret_cast<const u16x8*>(p0 + (size_t)kc*16384);
    #pragma unroll
    for (int e=0;e<8;e++) s[e] += bf2f(v[e]);
  }
  int t = qt*16 + qq;
  u16x8 w;
  #pragma unroll
  for (int e=0;e<8;e++) w[e] = f2bf(s[e]);
  *reinterpret_cast<u16x8*>(y + ((size_t)(b*1024 + t))*1024 + o*64 + d8*8) = w;
}

// ---------------- GEGLU: g[row][j] = gelu(ffu[row][j]) * ffu[row][j+3072] ----------------
__global__ void k_geglu(const uint16_t* __restrict__ ffu, uint16_t* __restrict__ g){
  int i = blockIdx.x*256 + threadIdx.x;      // 2048*384
  int row = i / 384, j8 = i - row*384;
  const uint16_t* pa = ffu + (size_t)row*6144 + j8*8;
  u16x8 a = *reinterpret_cast<const u16x8*>(pa);
  u16x8 b = *reinterpret_cast<const u16x8*>(pa + 3072);
  u16x8 o;
  #pragma unroll
  for (int e=0;e<8;e++){
    float xv = bf2f(a[e]);
    float gl = 0.5f*xv*(1.f + erff(xv*0.70710678118f));
    o[e] = f2bf(gl * bf2f(b[e]));
  }
  *reinterpret_cast<u16x8*>(g + (size_t)row*3072 + j8*8) = o;
}

// ---------------- host ----------------
extern "C" void kernel_launch(void* const* d_in, const int* in_sizes, int n_in,
                              void* d_out, int out_size, void* d_ws, size_t ws_size,
                              hipStream_t stream)
{
  const float* x      = (const float*)d_in[0];
  const float* ln1w   = (const float*)d_in[1];
  const float* ln1b   = (const float*)d_in[2];
  const float* ln2w   = (const float*)d_in[3];
  const float* ln2b   = (const float*)d_in[4];
  const float* Wq     = (const float*)d_in[5];
  const float* bq     = (const float*)d_in[6];
  const float* Wk     = (const float*)d_in[7];
  const float* bk     = (const float*)d_in[8];
  const float* Wv     = (const float*)d_in[9];
  const float* bv     = (const float*)d_in[10];
  const float* Wo     = (const float*)d_in[11];
  const float* bo     = (const float*)d_in[12];
  const float* tw     = (const float*)d_in[13];
  const float* talpha = (const float*)d_in[14];
  const float* tbeta  = (const float*)d_in[15];
  const float* tgamma = (const float*)d_in[16];
  const float* mixw   = (const float*)d_in[17];
  const float* Wkg    = (const float*)d_in[18];
  const float* bkg    = (const float*)d_in[19];
  const float* Wvg    = (const float*)d_in[20];
  const float* bvg    = (const float*)d_in[21];
  const float* Wwg    = (const float*)d_in[22];
  const float* bwg    = (const float*)d_in[23];

  char* ws = (char*)d_ws;
  size_t off = 0;
  auto alloc = [&](size_t bytes)->char*{
    char* p = ws + off; off += (bytes + 255) & ~(size_t)255; return p;
  };
  uint16_t* WqT  = (uint16_t*)alloc((size_t)C_*C_*2);     // contiguous q|k|v
  uint16_t* WkT  = (uint16_t*)alloc((size_t)C_*C_*2);
  uint16_t* WvT  = (uint16_t*)alloc((size_t)C_*C_*2);
  uint16_t* WoT  = (uint16_t*)alloc((size_t)C_*C_*2);
  uint16_t* WkgT = (uint16_t*)alloc((size_t)FFN_*C_*2);   // contiguous kg|vg
  uint16_t* WvgT = (uint16_t*)alloc((size_t)FFN_*C_*2);
  uint16_t* WwgT = (uint16_t*)alloc((size_t)C_*FFN_*2);
  uint16_t* xs   = (uint16_t*)alloc((size_t)B_*T_*C_*2);
  uint16_t* qbuf = (uint16_t*)alloc((size_t)B_*T_*C_*2);  // contiguous q|k|vT
  uint16_t* kbuf = (uint16_t*)alloc((size_t)B_*T_*C_*2);
  uint16_t* vT   = (uint16_t*)alloc((size_t)B_*T_*C_*2);
  float*    sm   = (float*)alloc((size_t)B_*H_*T_*4);
  float*    sl   = (float*)alloc((size_t)B_*H_*T_*4);
  uint16_t* ybuf = (uint16_t*)alloc((size_t)B_*T_*C_*2);
  float*    x1   = (float*)alloc((size_t)B_*T_*C_*4);
  float*    bcat = (float*)alloc((size_t)9216*4);
  char*     region = alloc((size_t)64*1024*1024);
  uint16_t* py  = (uint16_t*)region;                       // 32 MB bf16 partials
  uint16_t* ffu = (uint16_t*)region;                       // 25.2 MB (after attn done)
  uint16_t* gb  = (uint16_t*)(region + (size_t)2048*6144*2);

  if (off > ws_size){
    fprintf(stderr, "kernel_launch: ws too small (%zu needed, %zu given)\n", off, ws_size);
    return;
  }

  dim3 blk(256);
  dim3 tblk(32,8);
  k_transpose<<<dim3(32,32), tblk, 0, stream>>>(Wq,  WqT,  C_,  C_);
  k_transpose<<<dim3(32,32), tblk, 0, stream>>>(Wk,  WkT,  C_,  C_);
  k_transpose<<<dim3(32,32), tblk, 0, stream>>>(Wv,  WvT,  C_,  C_);
  k_transpose<<<dim3(32,32), tblk, 0, stream>>>(Wo,  WoT,  C_,  C_);
  k_transpose<<<dim3(96,32), tblk, 0, stream>>>(Wkg, WkgT, C_,  FFN_);
  k_transpose<<<dim3(96,32), tblk, 0, stream>>>(Wvg, WvgT, C_,  FFN_);
  k_transpose<<<dim3(32,96), tblk, 0, stream>>>(Wwg, WwgT, FFN_, C_);
  k_bcat<<<36, blk, 0, stream>>>(bq, bk, bv, bkg, bvg, bcat);

  k_ln<1><<<B_*T_, blk, 0, stream>>>(x, ln1w, ln1b, xs);

  // fused QKV (N=3072) with RoPE + scatter epilogue
  k_gemm2<EPI_QKV,64><<<dim3(48,16), blk, 0, stream>>>(xs, WqT, bcat, qbuf, 2048, 3072, 1024, nullptr, nullptr);

  k_stats<<<dim3(B_*H_, T_/64), blk, 0, stream>>>(qbuf, kbuf, sm, sl);
  k_attn<<<dim3(64,8,B_), dim3(512), 0, stream>>>(qbuf, kbuf, vT, sm, sl,
                                                  tw, talpha, tbeta, mixw, py);
  k_yred<<<1024, blk, 0, stream>>>(py, ybuf);

  k_gemm2<EPI_WO,64><<<dim3(16,16), blk, 0, stream>>>(ybuf, WoT, bo, x1, 2048, 1024, 1024, tgamma, x);

  k_ln<0><<<B_*T_, blk, 0, stream>>>(x1, ln2w, ln2b, xs);

  // fused FFN-up (N=6144)
  k_gemm2<EPI_BF16,128><<<dim3(48,16), blk, 0, stream>>>(xs, WkgT, bcat+3072, ffu, 2048, 6144, 1024, nullptr, nullptr);
  k_geglu<<<3072, blk, 0, stream>>>(ffu, gb);
  k_gemm2<EPI_FFN2,64><<<dim3(16,16), blk, 0, stream>>>(gb, WwgT, bwg, d_out, 2048, 1024, 3072, x1, nullptr);
}